// Round 8
// baseline (1543.360 us; speedup 1.0000x reference)
//
#include <hip/hip_runtime.h>
#include <math.h>

constexpr int B_ = 8;
constexpr int N_ = 1024;
constexpr int K_ = 20;
constexpr float EPS_ = 1e-5f;

typedef __attribute__((ext_vector_type(8))) short short8;
typedef __attribute__((ext_vector_type(4))) float f32x4;
typedef unsigned long long u64;

// hi/lo bf16 split (RNE both halves)
__device__ __forceinline__ void bf16split(float x, unsigned short& h, unsigned short& l) {
    unsigned u = __float_as_uint(x);
    unsigned rh = (u + 0x7FFFu + ((u >> 16) & 1u)) >> 16;
    h = (unsigned short)rh;
    float lof = x - __uint_as_float(rh << 16);
    unsigned ul = __float_as_uint(lof);
    l = (unsigned short)((ul + 0x7FFFu + ((ul >> 16) & 1u)) >> 16);
}

// ---------------------------------------------------------------- split + sq
template <int C, int CP>
__global__ __launch_bounds__(256) void split_kernel(const float* __restrict__ h,
                                                    unsigned short* __restrict__ Hh,
                                                    unsigned short* __restrict__ Hl,
                                                    float* __restrict__ sq) {
    int p = blockIdx.x * 256 + threadIdx.x;
    if (p >= B_ * N_) return;
    const float* r = h + (size_t)p * C;
    unsigned short hb[CP], lb[CP];
    float s = 0.f;
#pragma unroll
    for (int c = 0; c < C; ++c) {
        float v = r[c];
        s += v * v;
        bf16split(v, hb[c], lb[c]);
    }
#pragma unroll
    for (int c = C; c < CP; ++c) { hb[c] = 0; lb[c] = 0; }
    sq[p] = s;
#pragma unroll
    for (int i = 0; i < CP / 8; ++i) {
        *(short8*)&Hh[(size_t)p * CP + 8 * i] = *(const short8*)&hb[8 * i];
        *(short8*)&Hl[(size_t)p * CP + 8 * i] = *(const short8*)&lb[8 * i];
    }
}

// ---------------------------------------------------------------- distance GEMM
template <int CP>
__global__ __launch_bounds__(256) void distg_kernel(const unsigned short* __restrict__ Hh,
                                                    const unsigned short* __restrict__ Hl,
                                                    const float* __restrict__ sq,
                                                    float* __restrict__ dist) {
    constexpr int KC = CP / 32;
    constexpr int STR = 40;
    __shared__ unsigned short As[2][128 * STR];
    __shared__ unsigned short Bs[2][128 * STR];
    int t = threadIdx.x;
    int bid = blockIdx.x;
    int bb = bid >> 6;
    int r0 = ((bid >> 3) & 7) * 128;
    int c0 = (bid & 7) * 128;
    size_t base = (size_t)bb * N_;
    int lane = t & 63, wave = t >> 6, quad = lane >> 4, nl = lane & 15;
    int wm = wave >> 1, wn = wave & 1;

    f32x4 acc[4][4];
#pragma unroll
    for (int mt = 0; mt < 4; ++mt)
#pragma unroll
        for (int nt = 0; nt < 4; ++nt) acc[mt][nt] = (f32x4){0.f, 0.f, 0.f, 0.f};

    for (int kc = 0; kc < KC; ++kc) {
        if (kc) __syncthreads();
#pragma unroll
        for (int i = 0; i < 2; ++i) {
            int cid = t + i * 256;
            int row = cid >> 2, j = cid & 3;
            size_t asrc = (base + r0 + row) * CP + kc * 32 + 8 * j;
            size_t bsrc = (base + c0 + row) * CP + kc * 32 + 8 * j;
            int dst = row * STR + 8 * j;
            *(short8*)&As[0][dst] = *(const short8*)&Hh[asrc];
            *(short8*)&As[1][dst] = *(const short8*)&Hl[asrc];
            *(short8*)&Bs[0][dst] = *(const short8*)&Hh[bsrc];
            *(short8*)&Bs[1][dst] = *(const short8*)&Hl[bsrc];
        }
        __syncthreads();
        short8 ah[4], al[4];
#pragma unroll
        for (int mt = 0; mt < 4; ++mt) {
            int off = (wm * 64 + mt * 16 + nl) * STR + quad * 8;
            ah[mt] = *(const short8*)&As[0][off];
            al[mt] = *(const short8*)&As[1][off];
        }
#pragma unroll
        for (int nt = 0; nt < 4; ++nt) {
            int off = (wn * 64 + nt * 16 + nl) * STR + quad * 8;
            short8 bh = *(const short8*)&Bs[0][off];
            short8 bl = *(const short8*)&Bs[1][off];
#pragma unroll
            for (int mt = 0; mt < 4; ++mt) {
                acc[mt][nt] = __builtin_amdgcn_mfma_f32_16x16x32_bf16(ah[mt], bh, acc[mt][nt], 0, 0, 0);
                acc[mt][nt] = __builtin_amdgcn_mfma_f32_16x16x32_bf16(ah[mt], bl, acc[mt][nt], 0, 0, 0);
                acc[mt][nt] = __builtin_amdgcn_mfma_f32_16x16x32_bf16(al[mt], bh, acc[mt][nt], 0, 0, 0);
            }
        }
    }
    float sqc[4];
#pragma unroll
    for (int nt = 0; nt < 4; ++nt) sqc[nt] = sq[base + c0 + wn * 64 + nt * 16 + nl];
    float* dbase = dist + (size_t)bb * N_ * N_;
#pragma unroll
    for (int mt = 0; mt < 4; ++mt) {
#pragma unroll
        for (int r = 0; r < 4; ++r) {
            int row = r0 + wm * 64 + mt * 16 + quad * 4 + r;
            float sqr = sq[base + row];
#pragma unroll
            for (int nt = 0; nt < 4; ++nt)
                dbase[(size_t)row * N_ + c0 + wn * 64 + nt * 16 + nl] =
                    2.f * acc[mt][nt][r] - sqr - sqc[nt];
        }
    }
}

// ---------------------------------------------------------------- top-20 select
__device__ __forceinline__ unsigned int fkey(float f) {
    unsigned int u = __float_as_uint(f);
    return (u & 0x80000000u) ? ~u : (u | 0x80000000u);
}

// descending bitonic sort of 16 u64 keys (fully unrolled network)
__device__ __forceinline__ void sort16_desc(u64* v) {
#pragma unroll
    for (int k = 2; k <= 16; k <<= 1) {
#pragma unroll
        for (int j = k >> 1; j > 0; j >>= 1) {
#pragma unroll
            for (int i = 0; i < 16; ++i) {
                int l = i ^ j;
                if (l > i) {
                    bool dir = ((i & k) == 0);  // max-at-i region
                    u64 a = v[i], b = v[l];
                    bool sw = dir ? (a < b) : (a > b);
                    v[i] = sw ? b : a;
                    v[l] = sw ? a : b;
                }
            }
        }
    }
}

// log-depth mux: v[p] for p in [0,16); caller guards p==16
__device__ __forceinline__ u64 mux16(const u64* v, int p) {
    u64 t0[8], t1[4], t2[2];
    bool b0 = p & 1, b1 = p & 2, b2 = p & 4, b3 = p & 8;
#pragma unroll
    for (int i = 0; i < 8; ++i) t0[i] = b0 ? v[2 * i + 1] : v[2 * i];
#pragma unroll
    for (int i = 0; i < 4; ++i) t1[i] = b1 ? t0[2 * i + 1] : t0[2 * i];
#pragma unroll
    for (int i = 0; i < 2; ++i) t2[i] = b2 ? t1[2 * i + 1] : t1[2 * i];
    return b3 ? t2[1] : t2[0];
}

// Per-lane sorted lists (16 u64 keys) + 64-way tournament merge of the heads.
// Emits the exact top-20 SET per row (downstream is max-over-k: order-free).
__global__ __launch_bounds__(256) void sel_kernel(const float* __restrict__ dist,
                                                  int* __restrict__ idx) {
    int t = threadIdx.x;
    int bb = blockIdx.x / (N_ / 8);
    int r0 = (blockIdx.x % (N_ / 8)) * 8;
    int wave = t >> 6, lane = t & 63;
    int row0 = r0 + 2 * wave, row1 = row0 + 1;
    const float* d0 = dist + ((size_t)bb * N_ + row0) * N_;
    const float* d1 = dist + ((size_t)bb * N_ + row1) * N_;
    int c0 = lane * 16;
    u64 v0[16], v1[16];
#pragma unroll
    for (int i = 0; i < 4; ++i) {
        float4 a = *(const float4*)&d0[c0 + 4 * i];
        float4 b = *(const float4*)&d1[c0 + 4 * i];
        float av[4] = {a.x, a.y, a.z, a.w};
        float bv[4] = {b.x, b.y, b.z, b.w};
#pragma unroll
        for (int e = 0; e < 4; ++e) {
            int c = c0 + 4 * i + e;
            v0[4 * i + e] = ((u64)fkey(av[e]) << 32) | (unsigned int)(~c);
            v1[4 * i + e] = ((u64)fkey(bv[e]) << 32) | (unsigned int)(~c);
        }
    }
    sort16_desc(v0);
    sort16_desc(v1);

    int* op0 = idx + ((size_t)bb * N_ + row0) * K_;
    int* op1 = idx + ((size_t)bb * N_ + row1) * K_;

    u64 h0 = v0[0], h1 = v1[0];
    int p0 = 0, p1 = 0;
    for (int it = 0; it < K_; ++it) {
        u64 m0 = h0, m1 = h1;
#pragma unroll
        for (int off = 32; off; off >>= 1) {
            u64 o0 = __shfl_xor(m0, off);
            u64 o1 = __shfl_xor(m1, off);
            m0 = o0 > m0 ? o0 : m0;
            m1 = o1 > m1 ? o1 : m1;
        }
        if (lane == 0) {
            op0[it] = (int)(~(unsigned int)m0);
            op1[it] = (int)(~(unsigned int)m1);
        }
        bool own0 = (h0 == m0), own1 = (h1 == m1);
        p0 += own0;
        p1 += own1;
        u64 n0 = (p0 < 16) ? mux16(v0, p0) : 0ull;
        u64 n1 = (p1 < 16) ? mux16(v1, p1) : 0ull;
        h0 = own0 ? n0 : h0;
        h1 = own1 ? n1 : h1;
    }
}

// ---------------------------------------------------------------- fp32 weight prep (L1)
template <int CIN, int COUT>
__global__ __launch_bounds__(256) void prep_kernel(const float* __restrict__ w,
                                                   const float* __restrict__ g,
                                                   const float* __restrict__ bb,
                                                   const float* __restrict__ m,
                                                   const float* __restrict__ v,
                                                   float* __restrict__ wdT,
                                                   float* __restrict__ wcdT,
                                                   float* __restrict__ bias2) {
    int e = blockIdx.x * 256 + threadIdx.x;
    if (e >= CIN * COUT) return;
    int o = e % COUT;
    int i = e / COUT;
    float a = g[o] / sqrtf(v[o] + EPS_);
    float wd = w[o * 2 * CIN + i];
    wdT[e] = a * wd;
    wcdT[e] = a * (w[o * 2 * CIN + CIN + i] - wd);
    if (i == 0) bias2[o] = bb[o] - m[o] * a;
}

// ---------------------------------------------------------------- L1 Y|Z (fp32, CIN=3)
__global__ __launch_bounds__(256) void y1z1_kernel(const float* __restrict__ x,
                                                   const float* __restrict__ wdT,
                                                   const float* __restrict__ wcdT,
                                                   const float* __restrict__ bias2,
                                                   float* __restrict__ YZ) {
    int t = threadIdx.x;
    int p = blockIdx.x * 4 + (t >> 6);
    int o = t & 63;
    float x0 = x[3 * p], x1 = x[3 * p + 1], x2 = x[3 * p + 2];
    float y = x0 * wdT[o] + x1 * wdT[64 + o] + x2 * wdT[128 + o];
    float z = bias2[o] + x0 * wcdT[o] + x1 * wcdT[64 + o] + x2 * wcdT[128 + o];
    YZ[(size_t)p * 128 + o] = y;
    YZ[(size_t)p * 128 + 64 + o] = z;
}

// ---------------------------------------------------------------- MFMA weight prep (cat [Wd ; Wc-Wd])
template <int CIN, int COUT>
__global__ __launch_bounds__(256) void prep_mfma2(const float* __restrict__ w,
                                                  const float* __restrict__ g,
                                                  const float* __restrict__ bb,
                                                  const float* __restrict__ m,
                                                  const float* __restrict__ v,
                                                  unsigned short* __restrict__ Wh,
                                                  unsigned short* __restrict__ Wl,
                                                  float* __restrict__ bias2) {
    constexpr int NOUT = 2 * COUT;
    constexpr int NT = NOUT / 16;
    int e = blockIdx.x * 256 + threadIdx.x;
    if (e >= CIN * NOUT) return;
    int n = e % NOUT, k = e / NOUT;
    int o = (n < COUT) ? n : n - COUT;
    float a = g[o] / sqrtf(v[o] + EPS_);
    float wv = (n < COUT) ? a * w[o * 2 * CIN + k]
                          : a * (w[o * 2 * CIN + CIN + k] - w[o * 2 * CIN + k]);
    unsigned short h, l;
    bf16split(wv, h, l);
    int kc = k >> 5, ko = k & 31, quad = ko >> 3, j = ko & 7;
    int nt = n >> 4, nl = n & 15;
    size_t pos = ((size_t)(kc * NT + nt) * 64 + quad * 16 + nl) * 8 + j;
    Wh[pos] = h;
    Wl[pos] = l;
    if (k == 0) bias2[n] = (n < COUT) ? 0.f : (bb[o] - m[o] * a);
}

// ---------------------------------------------------------------- Y|Z GEMM (points x NOUT)
template <int CP, int NOUT>
__global__ __launch_bounds__(256) void gemmYZ_kernel(const unsigned short* __restrict__ Hh,
                                                     const unsigned short* __restrict__ Hl,
                                                     const unsigned short* __restrict__ Wh,
                                                     const unsigned short* __restrict__ Wl,
                                                     const float* __restrict__ bias2,
                                                     float* __restrict__ YZ) {
    constexpr int KC = CP / 32;
    constexpr int NTt = NOUT / 16;
    constexpr int STR = 40;
    __shared__ unsigned short As[2][128 * STR];
    int t = threadIdx.x;
    int m0 = blockIdx.x * 128;
    int n0 = blockIdx.y * 128;
    int lane = t & 63, wave = t >> 6, quad = lane >> 4, nl = lane & 15;
    int wm = wave >> 1, wn = wave & 1;

    f32x4 acc[4][4];
#pragma unroll
    for (int mt = 0; mt < 4; ++mt)
#pragma unroll
        for (int nt = 0; nt < 4; ++nt) acc[mt][nt] = (f32x4){0.f, 0.f, 0.f, 0.f};

    for (int kc = 0; kc < KC; ++kc) {
        if (kc) __syncthreads();
#pragma unroll
        for (int i = 0; i < 2; ++i) {
            int cid = t + i * 256;
            int row = cid >> 2, j = cid & 3;
            size_t src = ((size_t)(m0 + row)) * CP + kc * 32 + 8 * j;
            int dst = row * STR + 8 * j;
            *(short8*)&As[0][dst] = *(const short8*)&Hh[src];
            *(short8*)&As[1][dst] = *(const short8*)&Hl[src];
        }
        __syncthreads();
        short8 ah[4], al[4];
#pragma unroll
        for (int mt = 0; mt < 4; ++mt) {
            int off = (wm * 64 + mt * 16 + nl) * STR + quad * 8;
            ah[mt] = *(const short8*)&As[0][off];
            al[mt] = *(const short8*)&As[1][off];
        }
#pragma unroll
        for (int nt = 0; nt < 4; ++nt) {
            int ntg = (n0 >> 4) + wn * 4 + nt;
            size_t bpos = ((size_t)(kc * NTt + ntg) * 64 + lane) * 8;
            short8 bh = *(const short8*)&Wh[bpos];
            short8 bl = *(const short8*)&Wl[bpos];
#pragma unroll
            for (int mt = 0; mt < 4; ++mt) {
                acc[mt][nt] = __builtin_amdgcn_mfma_f32_16x16x32_bf16(ah[mt], bh, acc[mt][nt], 0, 0, 0);
                acc[mt][nt] = __builtin_amdgcn_mfma_f32_16x16x32_bf16(ah[mt], bl, acc[mt][nt], 0, 0, 0);
                acc[mt][nt] = __builtin_amdgcn_mfma_f32_16x16x32_bf16(al[mt], bh, acc[mt][nt], 0, 0, 0);
            }
        }
    }
#pragma unroll
    for (int nt = 0; nt < 4; ++nt) {
        int col = n0 + wn * 64 + nt * 16 + nl;
        float bv = bias2[col];
#pragma unroll
        for (int mt = 0; mt < 4; ++mt) {
#pragma unroll
            for (int r = 0; r < 4; ++r) {
                int row = m0 + wm * 64 + mt * 16 + quad * 4 + r;
                YZ[(size_t)row * NOUT + col] = acc[mt][nt][r] + bv;
            }
        }
    }
}

// ---------------------------------------------------------------- gather + max + lrelu
template <int COUT>
__global__ __launch_bounds__(256) void gathermax_kernel(const float* __restrict__ YZ,
                                                        const int* __restrict__ idx,
                                                        float* __restrict__ h) {
    constexpr int NOUT = 2 * COUT;
    constexpr int PPG = 256 / COUT;
    __shared__ int nidx[PPG][K_];
    int t = threadIdx.x;
    int p0 = blockIdx.x * PPG;
    if (t < PPG * K_) nidx[t / K_][t % K_] = idx[(size_t)(p0 + t / K_) * K_ + t % K_];
    __syncthreads();
    int pg = t / COUT;
    int o = t % COUT;
    int p = p0 + pg;
    size_t ybase = (size_t)(p >> 10) << 10;  // batch row base
    float m = -INFINITY;
#pragma unroll
    for (int k = 0; k < K_; ++k)
        m = fmaxf(m, YZ[(ybase + nidx[pg][k]) * NOUT + o]);
    float val = m + YZ[(size_t)p * NOUT + COUT + o];
    val = (val >= 0.f) ? val : 0.2f * val;
    h[(size_t)p * COUT + o] = val;
}

// ---------------------------------------------------------------- global max pool
template <int C>
__global__ __launch_bounds__(256) void pool_kernel(const float* __restrict__ h,
                                                   float* __restrict__ f, int off) {
    __shared__ float red[4][64];
    int bb = blockIdx.x / (C / 64);
    int c0 = (blockIdx.x % (C / 64)) * 64;
    int lane = threadIdx.x & 63, sl = threadIdx.x >> 6;
    int c = c0 + lane;
    const float* hb = h + (size_t)bb * N_ * C;
    float mx = -INFINITY;
    for (int n = sl * 256; n < sl * 256 + 256; ++n) mx = fmaxf(mx, hb[(size_t)n * C + c]);
    red[sl][lane] = mx;
    __syncthreads();
    if (sl == 0) {
        mx = fmaxf(fmaxf(red[0][lane], red[1][lane]), fmaxf(red[2][lane], red[3][lane]));
        f[bb * 384 + off + c] = mx;
    }
}

// ---------------------------------------------------------------- FC tail
__global__ __launch_bounds__(128) void fc_tail(
    const float* __restrict__ f, const float* __restrict__ f1w,
    const float* __restrict__ f1b, const float* __restrict__ n1g,
    const float* __restrict__ n1b, const float* __restrict__ n1m,
    const float* __restrict__ n1v, const float* __restrict__ f2w,
    const float* __restrict__ f2b, const float* __restrict__ n2g,
    const float* __restrict__ n2b, const float* __restrict__ n2m,
    const float* __restrict__ n2v, const float* __restrict__ f3w,
    const float* __restrict__ f3b, float* __restrict__ out) {
    __shared__ float fb[384];
    __shared__ float s1[128];
    __shared__ float s2[16];
    int bb = blockIdx.x, t = threadIdx.x;
    for (int j = t; j < 384; j += 128) fb[j] = f[bb * 384 + j];
    __syncthreads();
    float a = f1b[t];
    for (int j = 0; j < 384; ++j) a += f1w[t * 384 + j] * fb[j];
    a = (a - n1m[t]) * (n1g[t] / sqrtf(n1v[t] + EPS_)) + n1b[t];
    s1[t] = fmaxf(a, 0.f);
    __syncthreads();
    if (t < 16) {
        float a2 = f2b[t];
        for (int j = 0; j < 128; ++j) a2 += f2w[t * 128 + j] * s1[j];
        a2 = (a2 - n2m[t]) * (n2g[t] / sqrtf(n2v[t] + EPS_)) + n2b[t];
        s2[t] = fmaxf(a2, 0.f);
    }
    __syncthreads();
    if (t == 0) {
        float a3 = f3b[0];
        for (int j = 0; j < 16; ++j) a3 += f3w[j] * s2[j];
        out[bb] = a3;
    }
}

// ---------------------------------------------------------------- launch
extern "C" void kernel_launch(void* const* d_in, const int* in_sizes, int n_in,
                              void* d_out, int out_size, void* d_ws, size_t ws_size,
                              hipStream_t stream) {
    const float* x = (const float*)d_in[0];
    const float* cw[4] = {(const float*)d_in[1], (const float*)d_in[6],
                          (const float*)d_in[11], (const float*)d_in[16]};
    const float* cg[4] = {(const float*)d_in[2], (const float*)d_in[7],
                          (const float*)d_in[12], (const float*)d_in[17]};
    const float* cb[4] = {(const float*)d_in[3], (const float*)d_in[8],
                          (const float*)d_in[13], (const float*)d_in[18]};
    const float* cm[4] = {(const float*)d_in[4], (const float*)d_in[9],
                          (const float*)d_in[14], (const float*)d_in[19]};
    const float* cv[4] = {(const float*)d_in[5], (const float*)d_in[10],
                          (const float*)d_in[15], (const float*)d_in[20]};
    const float* f1w = (const float*)d_in[21];
    const float* f1b = (const float*)d_in[22];
    const float* n1g = (const float*)d_in[23];
    const float* n1b = (const float*)d_in[24];
    const float* n1m = (const float*)d_in[25];
    const float* n1v = (const float*)d_in[26];
    const float* f2w = (const float*)d_in[27];
    const float* f2b = (const float*)d_in[28];
    const float* n2g = (const float*)d_in[29];
    const float* n2b = (const float*)d_in[30];
    const float* n2m = (const float*)d_in[31];
    const float* n2v = (const float*)d_in[32];
    const float* f3w = (const float*)d_in[33];
    const float* f3b = (const float*)d_in[34];
    float* out = (float*)d_out;

    char* ws = (char*)d_ws;
    size_t off = 0;
    auto alloc = [&](size_t bytes) {
        void* p = ws + off;
        off += (bytes + 255) & ~(size_t)255;
        return p;
    };
    float* sq = (float*)alloc(B_ * N_ * 4);
    int* idx = (int*)alloc((size_t)B_ * N_ * K_ * 4);
    float* h1 = (float*)alloc((size_t)B_ * N_ * 64 * 4);
    float* h2 = (float*)alloc((size_t)B_ * N_ * 64 * 4);
    float* h3 = (float*)alloc((size_t)B_ * N_ * 128 * 4);
    float* h4 = (float*)alloc((size_t)B_ * N_ * 256 * 4);
    float* wd = (float*)alloc(3 * 64 * 4);
    float* wcd = (float*)alloc(3 * 64 * 4);
    float* b2 = (float*)alloc(512 * 4);
    float* f = (float*)alloc(B_ * 384 * 4);
    unsigned short* Wh = (unsigned short*)alloc((size_t)128 * 512 * 2);
    unsigned short* Wl = (unsigned short*)alloc((size_t)128 * 512 * 2);
    unsigned short* Hh = (unsigned short*)alloc((size_t)B_ * N_ * 128 * 2);
    unsigned short* Hl = (unsigned short*)alloc((size_t)B_ * N_ * 128 * 2);
    // dist (32 MB) and YZ (<=16 MB) have disjoint lifetimes within a layer: overlay.
    float* dist = (float*)alloc((size_t)B_ * N_ * N_ * 4);
    float* YZ = dist;
    (void)ws_size; (void)in_sizes; (void)n_in; (void)out_size;

    const int SELG = B_ * (N_ / 8);
    const int SG = (B_ * N_) / 256;
    const int DG = B_ * 64;
    const int GM = B_ * N_;  // points

    // ---- layer 1: 3 -> 64
    split_kernel<3, 32><<<SG, 256, 0, stream>>>(x, Hh, Hl, sq);
    distg_kernel<32><<<DG, 256, 0, stream>>>(Hh, Hl, sq, dist);
    sel_kernel<<<SELG, 256, 0, stream>>>(dist, idx);
    prep_kernel<3, 64><<<1, 256, 0, stream>>>(cw[0], cg[0], cb[0], cm[0], cv[0], wd, wcd, b2);
    y1z1_kernel<<<GM / 4, 256, 0, stream>>>(x, wd, wcd, b2, YZ);
    gathermax_kernel<64><<<GM / 4, 256, 0, stream>>>(YZ, idx, h1);

    // ---- layer 2: 64 -> 64
    split_kernel<64, 64><<<SG, 256, 0, stream>>>(h1, Hh, Hl, sq);
    distg_kernel<64><<<DG, 256, 0, stream>>>(Hh, Hl, sq, dist);
    sel_kernel<<<SELG, 256, 0, stream>>>(dist, idx);
    prep_mfma2<64, 64><<<(64 * 128 + 255) / 256, 256, 0, stream>>>(cw[1], cg[1], cb[1], cm[1], cv[1], Wh, Wl, b2);
    gemmYZ_kernel<64, 128><<<dim3(64, 1), 256, 0, stream>>>(Hh, Hl, Wh, Wl, b2, YZ);
    gathermax_kernel<64><<<GM / 4, 256, 0, stream>>>(YZ, idx, h2);

    // ---- layer 3: 64 -> 128
    split_kernel<64, 64><<<SG, 256, 0, stream>>>(h2, Hh, Hl, sq);
    distg_kernel<64><<<DG, 256, 0, stream>>>(Hh, Hl, sq, dist);
    sel_kernel<<<SELG, 256, 0, stream>>>(dist, idx);
    prep_mfma2<64, 128><<<(64 * 256 + 255) / 256, 256, 0, stream>>>(cw[2], cg[2], cb[2], cm[2], cv[2], Wh, Wl, b2);
    gemmYZ_kernel<64, 256><<<dim3(64, 2), 256, 0, stream>>>(Hh, Hl, Wh, Wl, b2, YZ);
    gathermax_kernel<128><<<GM / 2, 256, 0, stream>>>(YZ, idx, h3);

    // ---- layer 4: 128 -> 256
    split_kernel<128, 128><<<SG, 256, 0, stream>>>(h3, Hh, Hl, sq);
    distg_kernel<128><<<DG, 256, 0, stream>>>(Hh, Hl, sq, dist);
    sel_kernel<<<SELG, 256, 0, stream>>>(dist, idx);
    prep_mfma2<128, 256><<<(128 * 512 + 255) / 256, 256, 0, stream>>>(cw[3], cg[3], cb[3], cm[3], cv[3], Wh, Wl, b2);
    gemmYZ_kernel<128, 512><<<dim3(64, 4), 256, 0, stream>>>(Hh, Hl, Wh, Wl, b2, YZ);
    gathermax_kernel<256><<<GM, 256, 0, stream>>>(YZ, idx, h4);

    // ---- pooling + FC tail
    pool_kernel<128><<<B_ * 2, 256, 0, stream>>>(h3, f, 0);
    pool_kernel<256><<<B_ * 4, 256, 0, stream>>>(h4, f, 128);
    fc_tail<<<B_, 128, 0, stream>>>(f, f1w, f1b, n1g, n1b, n1m, n1v, f2w, f2b, n2g, n2b,
                                    n2m, n2v, f3w, f3b, out);
}

// Round 9
// 419.437 us; speedup vs baseline: 3.6796x; 3.6796x over previous
//
#include <hip/hip_runtime.h>
#include <math.h>

constexpr int B_ = 8;
constexpr int N_ = 1024;
constexpr int K_ = 20;
constexpr float EPS_ = 1e-5f;

typedef __attribute__((ext_vector_type(8))) short short8;
typedef __attribute__((ext_vector_type(4))) float f32x4;
typedef unsigned long long u64;

// hi/lo bf16 split (RNE both halves)
__device__ __forceinline__ void bf16split(float x, unsigned short& h, unsigned short& l) {
    unsigned u = __float_as_uint(x);
    unsigned rh = (u + 0x7FFFu + ((u >> 16) & 1u)) >> 16;
    h = (unsigned short)rh;
    float lof = x - __uint_as_float(rh << 16);
    unsigned ul = __float_as_uint(lof);
    l = (unsigned short)((ul + 0x7FFFu + ((ul >> 16) & 1u)) >> 16);
}

// ---------------------------------------------------------------- split + sq
template <int C, int CP>
__global__ __launch_bounds__(256) void split_kernel(const float* __restrict__ h,
                                                    unsigned short* __restrict__ Hh,
                                                    unsigned short* __restrict__ Hl,
                                                    float* __restrict__ sq) {
    int p = blockIdx.x * 256 + threadIdx.x;
    if (p >= B_ * N_) return;
    const float* r = h + (size_t)p * C;
    unsigned short hb[CP], lb[CP];
    float s = 0.f;
#pragma unroll
    for (int c = 0; c < C; ++c) {
        float v = r[c];
        s += v * v;
        bf16split(v, hb[c], lb[c]);
    }
#pragma unroll
    for (int c = C; c < CP; ++c) { hb[c] = 0; lb[c] = 0; }
    sq[p] = s;
#pragma unroll
    for (int i = 0; i < CP / 8; ++i) {
        *(short8*)&Hh[(size_t)p * CP + 8 * i] = *(const short8*)&hb[8 * i];
        *(short8*)&Hl[(size_t)p * CP + 8 * i] = *(const short8*)&lb[8 * i];
    }
}

// ---------------------------------------------------------------- distance GEMM
template <int CP>
__global__ __launch_bounds__(256) void distg_kernel(const unsigned short* __restrict__ Hh,
                                                    const unsigned short* __restrict__ Hl,
                                                    const float* __restrict__ sq,
                                                    float* __restrict__ dist) {
    constexpr int KC = CP / 32;
    constexpr int STR = 40;
    __shared__ unsigned short As[2][128 * STR];
    __shared__ unsigned short Bs[2][128 * STR];
    int t = threadIdx.x;
    int bid = blockIdx.x;
    int bb = bid >> 6;
    int r0 = ((bid >> 3) & 7) * 128;
    int c0 = (bid & 7) * 128;
    size_t base = (size_t)bb * N_;
    int lane = t & 63, wave = t >> 6, quad = lane >> 4, nl = lane & 15;
    int wm = wave >> 1, wn = wave & 1;

    f32x4 acc[4][4];
#pragma unroll
    for (int mt = 0; mt < 4; ++mt)
#pragma unroll
        for (int nt = 0; nt < 4; ++nt) acc[mt][nt] = (f32x4){0.f, 0.f, 0.f, 0.f};

    for (int kc = 0; kc < KC; ++kc) {
        if (kc) __syncthreads();
#pragma unroll
        for (int i = 0; i < 2; ++i) {
            int cid = t + i * 256;
            int row = cid >> 2, j = cid & 3;
            size_t asrc = (base + r0 + row) * CP + kc * 32 + 8 * j;
            size_t bsrc = (base + c0 + row) * CP + kc * 32 + 8 * j;
            int dst = row * STR + 8 * j;
            *(short8*)&As[0][dst] = *(const short8*)&Hh[asrc];
            *(short8*)&As[1][dst] = *(const short8*)&Hl[asrc];
            *(short8*)&Bs[0][dst] = *(const short8*)&Hh[bsrc];
            *(short8*)&Bs[1][dst] = *(const short8*)&Hl[bsrc];
        }
        __syncthreads();
        short8 ah[4], al[4];
#pragma unroll
        for (int mt = 0; mt < 4; ++mt) {
            int off = (wm * 64 + mt * 16 + nl) * STR + quad * 8;
            ah[mt] = *(const short8*)&As[0][off];
            al[mt] = *(const short8*)&As[1][off];
        }
#pragma unroll
        for (int nt = 0; nt < 4; ++nt) {
            int off = (wn * 64 + nt * 16 + nl) * STR + quad * 8;
            short8 bh = *(const short8*)&Bs[0][off];
            short8 bl = *(const short8*)&Bs[1][off];
#pragma unroll
            for (int mt = 0; mt < 4; ++mt) {
                acc[mt][nt] = __builtin_amdgcn_mfma_f32_16x16x32_bf16(ah[mt], bh, acc[mt][nt], 0, 0, 0);
                acc[mt][nt] = __builtin_amdgcn_mfma_f32_16x16x32_bf16(ah[mt], bl, acc[mt][nt], 0, 0, 0);
                acc[mt][nt] = __builtin_amdgcn_mfma_f32_16x16x32_bf16(al[mt], bh, acc[mt][nt], 0, 0, 0);
            }
        }
    }
    float sqc[4];
#pragma unroll
    for (int nt = 0; nt < 4; ++nt) sqc[nt] = sq[base + c0 + wn * 64 + nt * 16 + nl];
    float* dbase = dist + (size_t)bb * N_ * N_;
#pragma unroll
    for (int mt = 0; mt < 4; ++mt) {
#pragma unroll
        for (int r = 0; r < 4; ++r) {
            int row = r0 + wm * 64 + mt * 16 + quad * 4 + r;
            float sqr = sq[base + row];
#pragma unroll
            for (int nt = 0; nt < 4; ++nt)
                dbase[(size_t)row * N_ + c0 + wn * 64 + nt * 16 + nl] =
                    2.f * acc[mt][nt][r] - sqr - sqc[nt];
        }
    }
}

// ---------------------------------------------------------------- top-20 select
__device__ __forceinline__ unsigned int fkey(float f) {
    unsigned int u = __float_as_uint(f);
    return (u & 0x80000000u) ? ~u : (u | 0x80000000u);
}

__device__ __forceinline__ u64 tree16(const u64* v) {
    u64 t0[8];
#pragma unroll
    for (int s = 0; s < 8; ++s) t0[s] = v[2 * s] > v[2 * s + 1] ? v[2 * s] : v[2 * s + 1];
#pragma unroll
    for (int s = 0; s < 4; ++s) t0[s] = t0[2 * s] > t0[2 * s + 1] ? t0[2 * s] : t0[2 * s + 1];
    t0[0] = t0[0] > t0[1] ? t0[0] : t0[1];
    t0[2] = t0[2] > t0[3] ? t0[2] : t0[3];
    return t0[0] > t0[2] ? t0[0] : t0[2];
}

// full-wave bitonic sort (descending by lane) of ONE u64 per lane — no
// register arrays, no spill risk.
__device__ __forceinline__ u64 wave_sort_desc(u64 v, int lane) {
#pragma unroll
    for (int k2 = 2; k2 <= 64; k2 <<= 1) {
#pragma unroll
        for (int j = k2 >> 1; j > 0; j >>= 1) {
            u64 o = __shfl_xor(v, j);
            bool desc = ((lane & k2) == 0);
            bool lower = ((lane & j) == 0);
            u64 mx = v > o ? v : o;
            u64 mn = v > o ? o : v;
            v = (desc == lower) ? mx : mn;
        }
    }
    return v;
}

// One row per wave.  Threshold-filter: tau = 20th largest of the 64 per-lane
// maxes (>=20 values >= tau, so top-20 subset of {k >= tau}).  Compact
// candidates to LDS, one more wave sort, lanes 0..19 emit.  Wave-uniform
// fallback to the iterative loop if candidate count > 64 (rare).
__global__ __launch_bounds__(256) void sel_kernel(const float* __restrict__ dist,
                                                  int* __restrict__ idx) {
    __shared__ u64 cand[4][64];
    int t = threadIdx.x;
    int wave = t >> 6, lane = t & 63;
    int gr = blockIdx.x * 4 + wave;            // global row (b*N + r)
    const float* d = dist + (size_t)gr * N_;
    int* op = idx + (size_t)gr * K_;
    int c0 = lane * 16;

    u64 kk[16];
#pragma unroll
    for (int i = 0; i < 4; ++i) {
        float4 a = *(const float4*)&d[c0 + 4 * i];
        float av[4] = {a.x, a.y, a.z, a.w};
#pragma unroll
        for (int e = 0; e < 4; ++e) {
            int c = c0 + 4 * i + e;
            kk[4 * i + e] = ((u64)fkey(av[e]) << 32) | (unsigned int)(~c);
        }
    }

    // per-lane max, wave-sort it, tau = sorted[19]
    u64 lm = tree16(kk);
    u64 lms = wave_sort_desc(lm, lane);
    u64 tau = __shfl(lms, 19);

    // count candidates >= tau; exclusive prefix over lanes
    int cnt = 0;
#pragma unroll
    for (int i = 0; i < 16; ++i) cnt += (kk[i] >= tau) ? 1 : 0;
    int incl = cnt;
#pragma unroll
    for (int dd = 1; dd < 64; dd <<= 1) {
        int n = __shfl_up(incl, dd);
        if (lane >= dd) incl += n;
    }
    int excl = incl - cnt;
    int Ctot = __shfl(incl, 63);

    if (Ctot <= 64) {
        cand[wave][lane] = 0ull;
        __builtin_amdgcn_wave_barrier();
        int pos = excl;
#pragma unroll
        for (int i = 0; i < 16; ++i) {
            if (kk[i] >= tau) { cand[wave][pos] = kk[i]; ++pos; }
        }
        __builtin_amdgcn_wave_barrier();
        u64 c = cand[wave][lane];   // same-wave DS ops are in-order
        c = wave_sort_desc(c, lane);
        if (lane < K_) op[lane] = (int)(~(unsigned int)c);
    } else {
        // fallback: proven iterative extract-max (exact, any distribution)
        for (int it = 0; it < K_; ++it) {
            u64 m = tree16(kk);
#pragma unroll
            for (int off = 32; off; off >>= 1) {
                u64 o = __shfl_xor(m, off);
                m = o > m ? o : m;
            }
            if (lane == 0) op[it] = (int)(~(unsigned int)m);
#pragma unroll
            for (int j = 0; j < 16; ++j) kk[j] = (kk[j] == m) ? 0ull : kk[j];
        }
    }
}

// ---------------------------------------------------------------- fp32 weight prep (L1)
template <int CIN, int COUT>
__global__ __launch_bounds__(256) void prep_kernel(const float* __restrict__ w,
                                                   const float* __restrict__ g,
                                                   const float* __restrict__ bb,
                                                   const float* __restrict__ m,
                                                   const float* __restrict__ v,
                                                   float* __restrict__ wdT,
                                                   float* __restrict__ wcdT,
                                                   float* __restrict__ bias2) {
    int e = blockIdx.x * 256 + threadIdx.x;
    if (e >= CIN * COUT) return;
    int o = e % COUT;
    int i = e / COUT;
    float a = g[o] / sqrtf(v[o] + EPS_);
    float wd = w[o * 2 * CIN + i];
    wdT[e] = a * wd;
    wcdT[e] = a * (w[o * 2 * CIN + CIN + i] - wd);
    if (i == 0) bias2[o] = bb[o] - m[o] * a;
}

// ---------------------------------------------------------------- L1 Y|Z (fp32, CIN=3)
__global__ __launch_bounds__(256) void y1z1_kernel(const float* __restrict__ x,
                                                   const float* __restrict__ wdT,
                                                   const float* __restrict__ wcdT,
                                                   const float* __restrict__ bias2,
                                                   float* __restrict__ YZ) {
    int t = threadIdx.x;
    int p = blockIdx.x * 4 + (t >> 6);
    int o = t & 63;
    float x0 = x[3 * p], x1 = x[3 * p + 1], x2 = x[3 * p + 2];
    float y = x0 * wdT[o] + x1 * wdT[64 + o] + x2 * wdT[128 + o];
    float z = bias2[o] + x0 * wcdT[o] + x1 * wcdT[64 + o] + x2 * wcdT[128 + o];
    YZ[(size_t)p * 128 + o] = y;
    YZ[(size_t)p * 128 + 64 + o] = z;
}

// ---------------------------------------------------------------- MFMA weight prep (cat [Wd ; Wc-Wd])
template <int CIN, int COUT>
__global__ __launch_bounds__(256) void prep_mfma2(const float* __restrict__ w,
                                                  const float* __restrict__ g,
                                                  const float* __restrict__ bb,
                                                  const float* __restrict__ m,
                                                  const float* __restrict__ v,
                                                  unsigned short* __restrict__ Wh,
                                                  unsigned short* __restrict__ Wl,
                                                  float* __restrict__ bias2) {
    constexpr int NOUT = 2 * COUT;
    constexpr int NT = NOUT / 16;
    int e = blockIdx.x * 256 + threadIdx.x;
    if (e >= CIN * NOUT) return;
    int n = e % NOUT, k = e / NOUT;
    int o = (n < COUT) ? n : n - COUT;
    float a = g[o] / sqrtf(v[o] + EPS_);
    float wv = (n < COUT) ? a * w[o * 2 * CIN + k]
                          : a * (w[o * 2 * CIN + CIN + k] - w[o * 2 * CIN + k]);
    unsigned short h, l;
    bf16split(wv, h, l);
    int kc = k >> 5, ko = k & 31, quad = ko >> 3, j = ko & 7;
    int nt = n >> 4, nl = n & 15;
    size_t pos = ((size_t)(kc * NT + nt) * 64 + quad * 16 + nl) * 8 + j;
    Wh[pos] = h;
    Wl[pos] = l;
    if (k == 0) bias2[n] = (n < COUT) ? 0.f : (bb[o] - m[o] * a);
}

// ---------------------------------------------------------------- Y|Z GEMM (points x NOUT)
template <int CP, int NOUT>
__global__ __launch_bounds__(256) void gemmYZ_kernel(const unsigned short* __restrict__ Hh,
                                                     const unsigned short* __restrict__ Hl,
                                                     const unsigned short* __restrict__ Wh,
                                                     const unsigned short* __restrict__ Wl,
                                                     const float* __restrict__ bias2,
                                                     float* __restrict__ YZ) {
    constexpr int KC = CP / 32;
    constexpr int NTt = NOUT / 16;
    constexpr int STR = 40;
    __shared__ unsigned short As[2][128 * STR];
    int t = threadIdx.x;
    int m0 = blockIdx.x * 128;
    int n0 = blockIdx.y * 128;
    int lane = t & 63, wave = t >> 6, quad = lane >> 4, nl = lane & 15;
    int wm = wave >> 1, wn = wave & 1;

    f32x4 acc[4][4];
#pragma unroll
    for (int mt = 0; mt < 4; ++mt)
#pragma unroll
        for (int nt = 0; nt < 4; ++nt) acc[mt][nt] = (f32x4){0.f, 0.f, 0.f, 0.f};

    for (int kc = 0; kc < KC; ++kc) {
        if (kc) __syncthreads();
#pragma unroll
        for (int i = 0; i < 2; ++i) {
            int cid = t + i * 256;
            int row = cid >> 2, j = cid & 3;
            size_t src = ((size_t)(m0 + row)) * CP + kc * 32 + 8 * j;
            int dst = row * STR + 8 * j;
            *(short8*)&As[0][dst] = *(const short8*)&Hh[src];
            *(short8*)&As[1][dst] = *(const short8*)&Hl[src];
        }
        __syncthreads();
        short8 ah[4], al[4];
#pragma unroll
        for (int mt = 0; mt < 4; ++mt) {
            int off = (wm * 64 + mt * 16 + nl) * STR + quad * 8;
            ah[mt] = *(const short8*)&As[0][off];
            al[mt] = *(const short8*)&As[1][off];
        }
#pragma unroll
        for (int nt = 0; nt < 4; ++nt) {
            int ntg = (n0 >> 4) + wn * 4 + nt;
            size_t bpos = ((size_t)(kc * NTt + ntg) * 64 + lane) * 8;
            short8 bh = *(const short8*)&Wh[bpos];
            short8 bl = *(const short8*)&Wl[bpos];
#pragma unroll
            for (int mt = 0; mt < 4; ++mt) {
                acc[mt][nt] = __builtin_amdgcn_mfma_f32_16x16x32_bf16(ah[mt], bh, acc[mt][nt], 0, 0, 0);
                acc[mt][nt] = __builtin_amdgcn_mfma_f32_16x16x32_bf16(ah[mt], bl, acc[mt][nt], 0, 0, 0);
                acc[mt][nt] = __builtin_amdgcn_mfma_f32_16x16x32_bf16(al[mt], bh, acc[mt][nt], 0, 0, 0);
            }
        }
    }
#pragma unroll
    for (int nt = 0; nt < 4; ++nt) {
        int col = n0 + wn * 64 + nt * 16 + nl;
        float bv = bias2[col];
#pragma unroll
        for (int mt = 0; mt < 4; ++mt) {
#pragma unroll
            for (int r = 0; r < 4; ++r) {
                int row = m0 + wm * 64 + mt * 16 + quad * 4 + r;
                YZ[(size_t)row * NOUT + col] = acc[mt][nt][r] + bv;
            }
        }
    }
}

// ---------------------------------------------------------------- gather + max + lrelu
template <int COUT>
__global__ __launch_bounds__(256) void gathermax_kernel(const float* __restrict__ YZ,
                                                        const int* __restrict__ idx,
                                                        float* __restrict__ h) {
    constexpr int NOUT = 2 * COUT;
    constexpr int PPG = 256 / COUT;
    __shared__ int nidx[PPG][K_];
    int t = threadIdx.x;
    int p0 = blockIdx.x * PPG;
    if (t < PPG * K_) nidx[t / K_][t % K_] = idx[(size_t)(p0 + t / K_) * K_ + t % K_];
    __syncthreads();
    int pg = t / COUT;
    int o = t % COUT;
    int p = p0 + pg;
    size_t ybase = (size_t)(p >> 10) << 10;  // batch row base
    float m = -INFINITY;
#pragma unroll
    for (int k = 0; k < K_; ++k)
        m = fmaxf(m, YZ[(ybase + nidx[pg][k]) * NOUT + o]);
    float val = m + YZ[(size_t)p * NOUT + COUT + o];
    val = (val >= 0.f) ? val : 0.2f * val;
    h[(size_t)p * COUT + o] = val;
}

// ---------------------------------------------------------------- global max pool
template <int C>
__global__ __launch_bounds__(256) void pool_kernel(const float* __restrict__ h,
                                                   float* __restrict__ f, int off) {
    __shared__ float red[4][64];
    int bb = blockIdx.x / (C / 64);
    int c0 = (blockIdx.x % (C / 64)) * 64;
    int lane = threadIdx.x & 63, sl = threadIdx.x >> 6;
    int c = c0 + lane;
    const float* hb = h + (size_t)bb * N_ * C;
    float mx = -INFINITY;
    for (int n = sl * 256; n < sl * 256 + 256; ++n) mx = fmaxf(mx, hb[(size_t)n * C + c]);
    red[sl][lane] = mx;
    __syncthreads();
    if (sl == 0) {
        mx = fmaxf(fmaxf(red[0][lane], red[1][lane]), fmaxf(red[2][lane], red[3][lane]));
        f[bb * 384 + off + c] = mx;
    }
}

// ---------------------------------------------------------------- FC tail
__global__ __launch_bounds__(128) void fc_tail(
    const float* __restrict__ f, const float* __restrict__ f1w,
    const float* __restrict__ f1b, const float* __restrict__ n1g,
    const float* __restrict__ n1b, const float* __restrict__ n1m,
    const float* __restrict__ n1v, const float* __restrict__ f2w,
    const float* __restrict__ f2b, const float* __restrict__ n2g,
    const float* __restrict__ n2b, const float* __restrict__ n2m,
    const float* __restrict__ n2v, const float* __restrict__ f3w,
    const float* __restrict__ f3b, float* __restrict__ out) {
    __shared__ float fb[384];
    __shared__ float s1[128];
    __shared__ float s2[16];
    int bb = blockIdx.x, t = threadIdx.x;
    for (int j = t; j < 384; j += 128) fb[j] = f[bb * 384 + j];
    __syncthreads();
    float a = f1b[t];
    for (int j = 0; j < 384; ++j) a += f1w[t * 384 + j] * fb[j];
    a = (a - n1m[t]) * (n1g[t] / sqrtf(n1v[t] + EPS_)) + n1b[t];
    s1[t] = fmaxf(a, 0.f);
    __syncthreads();
    if (t < 16) {
        float a2 = f2b[t];
        for (int j = 0; j < 128; ++j) a2 += f2w[t * 128 + j] * s1[j];
        a2 = (a2 - n2m[t]) * (n2g[t] / sqrtf(n2v[t] + EPS_)) + n2b[t];
        s2[t] = fmaxf(a2, 0.f);
    }
    __syncthreads();
    if (t == 0) {
        float a3 = f3b[0];
        for (int j = 0; j < 16; ++j) a3 += f3w[j] * s2[j];
        out[bb] = a3;
    }
}

// ---------------------------------------------------------------- launch
extern "C" void kernel_launch(void* const* d_in, const int* in_sizes, int n_in,
                              void* d_out, int out_size, void* d_ws, size_t ws_size,
                              hipStream_t stream) {
    const float* x = (const float*)d_in[0];
    const float* cw[4] = {(const float*)d_in[1], (const float*)d_in[6],
                          (const float*)d_in[11], (const float*)d_in[16]};
    const float* cg[4] = {(const float*)d_in[2], (const float*)d_in[7],
                          (const float*)d_in[12], (const float*)d_in[17]};
    const float* cb[4] = {(const float*)d_in[3], (const float*)d_in[8],
                          (const float*)d_in[13], (const float*)d_in[18]};
    const float* cm[4] = {(const float*)d_in[4], (const float*)d_in[9],
                          (const float*)d_in[14], (const float*)d_in[19]};
    const float* cv[4] = {(const float*)d_in[5], (const float*)d_in[10],
                          (const float*)d_in[15], (const float*)d_in[20]};
    const float* f1w = (const float*)d_in[21];
    const float* f1b = (const float*)d_in[22];
    const float* n1g = (const float*)d_in[23];
    const float* n1b = (const float*)d_in[24];
    const float* n1m = (const float*)d_in[25];
    const float* n1v = (const float*)d_in[26];
    const float* f2w = (const float*)d_in[27];
    const float* f2b = (const float*)d_in[28];
    const float* n2g = (const float*)d_in[29];
    const float* n2b = (const float*)d_in[30];
    const float* n2m = (const float*)d_in[31];
    const float* n2v = (const float*)d_in[32];
    const float* f3w = (const float*)d_in[33];
    const float* f3b = (const float*)d_in[34];
    float* out = (float*)d_out;

    char* ws = (char*)d_ws;
    size_t off = 0;
    auto alloc = [&](size_t bytes) {
        void* p = ws + off;
        off += (bytes + 255) & ~(size_t)255;
        return p;
    };
    float* sq = (float*)alloc(B_ * N_ * 4);
    int* idx = (int*)alloc((size_t)B_ * N_ * K_ * 4);
    float* h1 = (float*)alloc((size_t)B_ * N_ * 64 * 4);
    float* h2 = (float*)alloc((size_t)B_ * N_ * 64 * 4);
    float* h3 = (float*)alloc((size_t)B_ * N_ * 128 * 4);
    float* h4 = (float*)alloc((size_t)B_ * N_ * 256 * 4);
    float* wd = (float*)alloc(3 * 64 * 4);
    float* wcd = (float*)alloc(3 * 64 * 4);
    float* b2 = (float*)alloc(512 * 4);
    float* f = (float*)alloc(B_ * 384 * 4);
    unsigned short* Wh = (unsigned short*)alloc((size_t)128 * 512 * 2);
    unsigned short* Wl = (unsigned short*)alloc((size_t)128 * 512 * 2);
    unsigned short* Hh = (unsigned short*)alloc((size_t)B_ * N_ * 128 * 2);
    unsigned short* Hl = (unsigned short*)alloc((size_t)B_ * N_ * 128 * 2);
    // dist (32 MB) and YZ (<=16 MB) have disjoint lifetimes within a layer: overlay.
    float* dist = (float*)alloc((size_t)B_ * N_ * N_ * 4);
    float* YZ = dist;
    (void)ws_size; (void)in_sizes; (void)n_in; (void)out_size;

    const int SELG = B_ * (N_ / 4);  // 1 row/wave, 4 rows/block
    const int SG = (B_ * N_) / 256;
    const int DG = B_ * 64;
    const int GM = B_ * N_;  // points

    // ---- layer 1: 3 -> 64
    split_kernel<3, 32><<<SG, 256, 0, stream>>>(x, Hh, Hl, sq);
    distg_kernel<32><<<DG, 256, 0, stream>>>(Hh, Hl, sq, dist);
    sel_kernel<<<SELG, 256, 0, stream>>>(dist, idx);
    prep_kernel<3, 64><<<1, 256, 0, stream>>>(cw[0], cg[0], cb[0], cm[0], cv[0], wd, wcd, b2);
    y1z1_kernel<<<GM / 4, 256, 0, stream>>>(x, wd, wcd, b2, YZ);
    gathermax_kernel<64><<<GM / 4, 256, 0, stream>>>(YZ, idx, h1);

    // ---- layer 2: 64 -> 64
    split_kernel<64, 64><<<SG, 256, 0, stream>>>(h1, Hh, Hl, sq);
    distg_kernel<64><<<DG, 256, 0, stream>>>(Hh, Hl, sq, dist);
    sel_kernel<<<SELG, 256, 0, stream>>>(dist, idx);
    prep_mfma2<64, 64><<<(64 * 128 + 255) / 256, 256, 0, stream>>>(cw[1], cg[1], cb[1], cm[1], cv[1], Wh, Wl, b2);
    gemmYZ_kernel<64, 128><<<dim3(64, 1), 256, 0, stream>>>(Hh, Hl, Wh, Wl, b2, YZ);
    gathermax_kernel<64><<<GM / 4, 256, 0, stream>>>(YZ, idx, h2);

    // ---- layer 3: 64 -> 128
    split_kernel<64, 64><<<SG, 256, 0, stream>>>(h2, Hh, Hl, sq);
    distg_kernel<64><<<DG, 256, 0, stream>>>(Hh, Hl, sq, dist);
    sel_kernel<<<SELG, 256, 0, stream>>>(dist, idx);
    prep_mfma2<64, 128><<<(64 * 256 + 255) / 256, 256, 0, stream>>>(cw[2], cg[2], cb[2], cm[2], cv[2], Wh, Wl, b2);
    gemmYZ_kernel<64, 256><<<dim3(64, 2), 256, 0, stream>>>(Hh, Hl, Wh, Wl, b2, YZ);
    gathermax_kernel<128><<<GM / 2, 256, 0, stream>>>(YZ, idx, h3);

    // ---- layer 4: 128 -> 256
    split_kernel<128, 128><<<SG, 256, 0, stream>>>(h3, Hh, Hl, sq);
    distg_kernel<128><<<DG, 256, 0, stream>>>(Hh, Hl, sq, dist);
    sel_kernel<<<SELG, 256, 0, stream>>>(dist, idx);
    prep_mfma2<128, 256><<<(128 * 512 + 255) / 256, 256, 0, stream>>>(cw[3], cg[3], cb[3], cm[3], cv[3], Wh, Wl, b2);
    gemmYZ_kernel<128, 512><<<dim3(64, 4), 256, 0, stream>>>(Hh, Hl, Wh, Wl, b2, YZ);
    gathermax_kernel<256><<<GM, 256, 0, stream>>>(YZ, idx, h4);

    // ---- pooling + FC tail
    pool_kernel<128><<<B_ * 2, 256, 0, stream>>>(h3, f, 0);
    pool_kernel<256><<<B_ * 4, 256, 0, stream>>>(h4, f, 128);
    fc_tail<<<B_, 128, 0, stream>>>(f, f1w, f1b, n1g, n1b, n1m, n1v, f2w, f2b, n2g, n2b,
                                    n2m, n2v, f3w, f3b, out);
}

// Round 10
// 344.860 us; speedup vs baseline: 4.4753x; 1.2163x over previous
//
#include <hip/hip_runtime.h>
#include <math.h>

constexpr int B_ = 8;
constexpr int N_ = 1024;
constexpr int K_ = 20;
constexpr float EPS_ = 1e-5f;

typedef __attribute__((ext_vector_type(8))) short short8;
typedef __attribute__((ext_vector_type(4))) float f32x4;
typedef unsigned long long u64;

// hi/lo bf16 split (RNE both halves)
__device__ __forceinline__ void bf16split(float x, unsigned short& h, unsigned short& l) {
    unsigned u = __float_as_uint(x);
    unsigned rh = (u + 0x7FFFu + ((u >> 16) & 1u)) >> 16;
    h = (unsigned short)rh;
    float lof = x - __uint_as_float(rh << 16);
    unsigned ul = __float_as_uint(lof);
    l = (unsigned short)((ul + 0x7FFFu + ((ul >> 16) & 1u)) >> 16);
}

// ---------------------------------------------------------------- split + sq
template <int C, int CP>
__global__ __launch_bounds__(256) void split_kernel(const float* __restrict__ h,
                                                    unsigned short* __restrict__ Hh,
                                                    unsigned short* __restrict__ Hl,
                                                    float* __restrict__ sq) {
    int p = blockIdx.x * 256 + threadIdx.x;
    if (p >= B_ * N_) return;
    const float* r = h + (size_t)p * C;
    unsigned short hb[CP], lb[CP];
    float s = 0.f;
#pragma unroll
    for (int c = 0; c < C; ++c) {
        float v = r[c];
        s += v * v;
        bf16split(v, hb[c], lb[c]);
    }
#pragma unroll
    for (int c = C; c < CP; ++c) { hb[c] = 0; lb[c] = 0; }
    sq[p] = s;
#pragma unroll
    for (int i = 0; i < CP / 8; ++i) {
        *(short8*)&Hh[(size_t)p * CP + 8 * i] = *(const short8*)&hb[8 * i];
        *(short8*)&Hl[(size_t)p * CP + 8 * i] = *(const short8*)&lb[8 * i];
    }
}

// ---------------------------------------------------------------- distance GEMM
template <int CP>
__global__ __launch_bounds__(256) void distg_kernel(const unsigned short* __restrict__ Hh,
                                                    const unsigned short* __restrict__ Hl,
                                                    const float* __restrict__ sq,
                                                    float* __restrict__ dist) {
    constexpr int KC = CP / 32;
    constexpr int STR = 40;
    __shared__ unsigned short As[2][128 * STR];
    __shared__ unsigned short Bs[2][128 * STR];
    int t = threadIdx.x;
    int bid = blockIdx.x;
    int bb = bid >> 6;
    int r0 = ((bid >> 3) & 7) * 128;
    int c0 = (bid & 7) * 128;
    size_t base = (size_t)bb * N_;
    int lane = t & 63, wave = t >> 6, quad = lane >> 4, nl = lane & 15;
    int wm = wave >> 1, wn = wave & 1;

    f32x4 acc[4][4];
#pragma unroll
    for (int mt = 0; mt < 4; ++mt)
#pragma unroll
        for (int nt = 0; nt < 4; ++nt) acc[mt][nt] = (f32x4){0.f, 0.f, 0.f, 0.f};

    for (int kc = 0; kc < KC; ++kc) {
        if (kc) __syncthreads();
#pragma unroll
        for (int i = 0; i < 2; ++i) {
            int cid = t + i * 256;
            int row = cid >> 2, j = cid & 3;
            size_t asrc = (base + r0 + row) * CP + kc * 32 + 8 * j;
            size_t bsrc = (base + c0 + row) * CP + kc * 32 + 8 * j;
            int dst = row * STR + 8 * j;
            *(short8*)&As[0][dst] = *(const short8*)&Hh[asrc];
            *(short8*)&As[1][dst] = *(const short8*)&Hl[asrc];
            *(short8*)&Bs[0][dst] = *(const short8*)&Hh[bsrc];
            *(short8*)&Bs[1][dst] = *(const short8*)&Hl[bsrc];
        }
        __syncthreads();
        short8 ah[4], al[4];
#pragma unroll
        for (int mt = 0; mt < 4; ++mt) {
            int off = (wm * 64 + mt * 16 + nl) * STR + quad * 8;
            ah[mt] = *(const short8*)&As[0][off];
            al[mt] = *(const short8*)&As[1][off];
        }
#pragma unroll
        for (int nt = 0; nt < 4; ++nt) {
            int off = (wn * 64 + nt * 16 + nl) * STR + quad * 8;
            short8 bh = *(const short8*)&Bs[0][off];
            short8 bl = *(const short8*)&Bs[1][off];
#pragma unroll
            for (int mt = 0; mt < 4; ++mt) {
                acc[mt][nt] = __builtin_amdgcn_mfma_f32_16x16x32_bf16(ah[mt], bh, acc[mt][nt], 0, 0, 0);
                acc[mt][nt] = __builtin_amdgcn_mfma_f32_16x16x32_bf16(ah[mt], bl, acc[mt][nt], 0, 0, 0);
                acc[mt][nt] = __builtin_amdgcn_mfma_f32_16x16x32_bf16(al[mt], bh, acc[mt][nt], 0, 0, 0);
            }
        }
    }
    float sqc[4];
#pragma unroll
    for (int nt = 0; nt < 4; ++nt) sqc[nt] = sq[base + c0 + wn * 64 + nt * 16 + nl];
    float* dbase = dist + (size_t)bb * N_ * N_;
#pragma unroll
    for (int mt = 0; mt < 4; ++mt) {
#pragma unroll
        for (int r = 0; r < 4; ++r) {
            int row = r0 + wm * 64 + mt * 16 + quad * 4 + r;
            float sqr = sq[base + row];
#pragma unroll
            for (int nt = 0; nt < 4; ++nt)
                dbase[(size_t)row * N_ + c0 + wn * 64 + nt * 16 + nl] =
                    2.f * acc[mt][nt][r] - sqr - sqc[nt];
        }
    }
}

// ---------------------------------------------------------------- top-20 select
__device__ __forceinline__ unsigned int fkey(float f) {
    unsigned int u = __float_as_uint(f);
    return (u & 0x80000000u) ? ~u : (u | 0x80000000u);
}

__device__ __forceinline__ u64 tree16(const u64* v) {
    u64 t0[8];
#pragma unroll
    for (int s = 0; s < 8; ++s) t0[s] = v[2 * s] > v[2 * s + 1] ? v[2 * s] : v[2 * s + 1];
#pragma unroll
    for (int s = 0; s < 4; ++s) t0[s] = t0[2 * s] > t0[2 * s + 1] ? t0[2 * s] : t0[2 * s + 1];
    t0[0] = t0[0] > t0[1] ? t0[0] : t0[1];
    t0[2] = t0[2] > t0[3] ? t0[2] : t0[3];
    return t0[0] > t0[2] ? t0[0] : t0[2];
}

// full-wave bitonic sort (descending by lane) of ONE u64 per lane
__device__ __forceinline__ u64 wave_sort_desc(u64 v, int lane) {
#pragma unroll
    for (int k2 = 2; k2 <= 64; k2 <<= 1) {
#pragma unroll
        for (int j = k2 >> 1; j > 0; j >>= 1) {
            u64 o = __shfl_xor(v, j);
            bool desc = ((lane & k2) == 0);
            bool lower = ((lane & j) == 0);
            u64 mx = v > o ? v : o;
            u64 mn = v > o ? o : v;
            v = (desc == lower) ? mx : mn;
        }
    }
    return v;
}

// One row per wave.  Threshold-filter top-20 (exact set; fallback exact loop).
__global__ __launch_bounds__(256) void sel_kernel(const float* __restrict__ dist,
                                                  int* __restrict__ idx) {
    __shared__ u64 cand[4][64];
    int t = threadIdx.x;
    int wave = t >> 6, lane = t & 63;
    int gr = blockIdx.x * 4 + wave;            // global row (b*N + r)
    const float* d = dist + (size_t)gr * N_;
    int* op = idx + (size_t)gr * K_;
    int c0 = lane * 16;

    u64 kk[16];
#pragma unroll
    for (int i = 0; i < 4; ++i) {
        float4 a = *(const float4*)&d[c0 + 4 * i];
        float av[4] = {a.x, a.y, a.z, a.w};
#pragma unroll
        for (int e = 0; e < 4; ++e) {
            int c = c0 + 4 * i + e;
            kk[4 * i + e] = ((u64)fkey(av[e]) << 32) | (unsigned int)(~c);
        }
    }

    u64 lm = tree16(kk);
    u64 lms = wave_sort_desc(lm, lane);
    u64 tau = __shfl(lms, 19);

    int cnt = 0;
#pragma unroll
    for (int i = 0; i < 16; ++i) cnt += (kk[i] >= tau) ? 1 : 0;
    int incl = cnt;
#pragma unroll
    for (int dd = 1; dd < 64; dd <<= 1) {
        int n = __shfl_up(incl, dd);
        if (lane >= dd) incl += n;
    }
    int excl = incl - cnt;
    int Ctot = __shfl(incl, 63);

    if (Ctot <= 64) {
        cand[wave][lane] = 0ull;
        __builtin_amdgcn_wave_barrier();
        int pos = excl;
#pragma unroll
        for (int i = 0; i < 16; ++i) {
            if (kk[i] >= tau) { cand[wave][pos] = kk[i]; ++pos; }
        }
        __builtin_amdgcn_wave_barrier();
        u64 c = cand[wave][lane];
        c = wave_sort_desc(c, lane);
        if (lane < K_) op[lane] = (int)(~(unsigned int)c);
    } else {
        for (int it = 0; it < K_; ++it) {
            u64 m = tree16(kk);
#pragma unroll
            for (int off = 32; off; off >>= 1) {
                u64 o = __shfl_xor(m, off);
                m = o > m ? o : m;
            }
            if (lane == 0) op[it] = (int)(~(unsigned int)m);
#pragma unroll
            for (int j = 0; j < 16; ++j) kk[j] = (kk[j] == m) ? 0ull : kk[j];
        }
    }
}

// ---------------------------------------------------------------- fp32 weight prep (L1)
template <int CIN, int COUT>
__global__ __launch_bounds__(256) void prep_kernel(const float* __restrict__ w,
                                                   const float* __restrict__ g,
                                                   const float* __restrict__ bb,
                                                   const float* __restrict__ m,
                                                   const float* __restrict__ v,
                                                   float* __restrict__ wdT,
                                                   float* __restrict__ wcdT,
                                                   float* __restrict__ bias2) {
    int e = blockIdx.x * 256 + threadIdx.x;
    if (e >= CIN * COUT) return;
    int o = e % COUT;
    int i = e / COUT;
    float a = g[o] / sqrtf(v[o] + EPS_);
    float wd = w[o * 2 * CIN + i];
    wdT[e] = a * wd;
    wcdT[e] = a * (w[o * 2 * CIN + CIN + i] - wd);
    if (i == 0) bias2[o] = bb[o] - m[o] * a;
}

// ---------------------------------------------------------------- L1 Y|Z (fp32, CIN=3)
__global__ __launch_bounds__(256) void y1z1_kernel(const float* __restrict__ x,
                                                   const float* __restrict__ wdT,
                                                   const float* __restrict__ wcdT,
                                                   const float* __restrict__ bias2,
                                                   float* __restrict__ YZ) {
    int t = threadIdx.x;
    int p = blockIdx.x * 4 + (t >> 6);
    int o = t & 63;
    float x0 = x[3 * p], x1 = x[3 * p + 1], x2 = x[3 * p + 2];
    float y = x0 * wdT[o] + x1 * wdT[64 + o] + x2 * wdT[128 + o];
    float z = bias2[o] + x0 * wcdT[o] + x1 * wcdT[64 + o] + x2 * wcdT[128 + o];
    YZ[(size_t)p * 128 + o] = y;
    YZ[(size_t)p * 128 + 64 + o] = z;
}

// ---------------------------------------------------------------- MFMA weight prep (cat [Wd ; Wc-Wd])
template <int CIN, int COUT>
__global__ __launch_bounds__(256) void prep_mfma2(const float* __restrict__ w,
                                                  const float* __restrict__ g,
                                                  const float* __restrict__ bb,
                                                  const float* __restrict__ m,
                                                  const float* __restrict__ v,
                                                  unsigned short* __restrict__ Wh,
                                                  unsigned short* __restrict__ Wl,
                                                  float* __restrict__ bias2) {
    constexpr int NOUT = 2 * COUT;
    constexpr int NT = NOUT / 16;
    int e = blockIdx.x * 256 + threadIdx.x;
    if (e >= CIN * NOUT) return;
    int n = e % NOUT, k = e / NOUT;
    int o = (n < COUT) ? n : n - COUT;
    float a = g[o] / sqrtf(v[o] + EPS_);
    float wv = (n < COUT) ? a * w[o * 2 * CIN + k]
                          : a * (w[o * 2 * CIN + CIN + k] - w[o * 2 * CIN + k]);
    unsigned short h, l;
    bf16split(wv, h, l);
    int kc = k >> 5, ko = k & 31, quad = ko >> 3, j = ko & 7;
    int nt = n >> 4, nl = n & 15;
    size_t pos = ((size_t)(kc * NT + nt) * 64 + quad * 16 + nl) * 8 + j;
    Wh[pos] = h;
    Wl[pos] = l;
    if (k == 0) bias2[n] = (n < COUT) ? 0.f : (bb[o] - m[o] * a);
}

// ---------------------------------------------------------------- Y|Z GEMM (points x NOUT)
template <int CP, int NOUT>
__global__ __launch_bounds__(256) void gemmYZ_kernel(const unsigned short* __restrict__ Hh,
                                                     const unsigned short* __restrict__ Hl,
                                                     const unsigned short* __restrict__ Wh,
                                                     const unsigned short* __restrict__ Wl,
                                                     const float* __restrict__ bias2,
                                                     float* __restrict__ YZ) {
    constexpr int KC = CP / 32;
    constexpr int NTt = NOUT / 16;
    constexpr int STR = 40;
    __shared__ unsigned short As[2][128 * STR];
    int t = threadIdx.x;
    int m0 = blockIdx.x * 128;
    int n0 = blockIdx.y * 128;
    int lane = t & 63, wave = t >> 6, quad = lane >> 4, nl = lane & 15;
    int wm = wave >> 1, wn = wave & 1;

    f32x4 acc[4][4];
#pragma unroll
    for (int mt = 0; mt < 4; ++mt)
#pragma unroll
        for (int nt = 0; nt < 4; ++nt) acc[mt][nt] = (f32x4){0.f, 0.f, 0.f, 0.f};

    for (int kc = 0; kc < KC; ++kc) {
        if (kc) __syncthreads();
#pragma unroll
        for (int i = 0; i < 2; ++i) {
            int cid = t + i * 256;
            int row = cid >> 2, j = cid & 3;
            size_t src = ((size_t)(m0 + row)) * CP + kc * 32 + 8 * j;
            int dst = row * STR + 8 * j;
            *(short8*)&As[0][dst] = *(const short8*)&Hh[src];
            *(short8*)&As[1][dst] = *(const short8*)&Hl[src];
        }
        __syncthreads();
        short8 ah[4], al[4];
#pragma unroll
        for (int mt = 0; mt < 4; ++mt) {
            int off = (wm * 64 + mt * 16 + nl) * STR + quad * 8;
            ah[mt] = *(const short8*)&As[0][off];
            al[mt] = *(const short8*)&As[1][off];
        }
#pragma unroll
        for (int nt = 0; nt < 4; ++nt) {
            int ntg = (n0 >> 4) + wn * 4 + nt;
            size_t bpos = ((size_t)(kc * NTt + ntg) * 64 + lane) * 8;
            short8 bh = *(const short8*)&Wh[bpos];
            short8 bl = *(const short8*)&Wl[bpos];
#pragma unroll
            for (int mt = 0; mt < 4; ++mt) {
                acc[mt][nt] = __builtin_amdgcn_mfma_f32_16x16x32_bf16(ah[mt], bh, acc[mt][nt], 0, 0, 0);
                acc[mt][nt] = __builtin_amdgcn_mfma_f32_16x16x32_bf16(ah[mt], bl, acc[mt][nt], 0, 0, 0);
                acc[mt][nt] = __builtin_amdgcn_mfma_f32_16x16x32_bf16(al[mt], bh, acc[mt][nt], 0, 0, 0);
            }
        }
    }
#pragma unroll
    for (int nt = 0; nt < 4; ++nt) {
        int col = n0 + wn * 64 + nt * 16 + nl;
        float bv = bias2[col];
#pragma unroll
        for (int mt = 0; mt < 4; ++mt) {
#pragma unroll
            for (int r = 0; r < 4; ++r) {
                int row = m0 + wm * 64 + mt * 16 + quad * 4 + r;
                YZ[(size_t)row * NOUT + col] = acc[mt][nt][r] + bv;
            }
        }
    }
}

// ---------------------------------------------------------------- gather + max + lrelu
template <int COUT>
__global__ __launch_bounds__(256) void gathermax_kernel(const float* __restrict__ YZ,
                                                        const int* __restrict__ idx,
                                                        float* __restrict__ h) {
    constexpr int NOUT = 2 * COUT;
    constexpr int PPG = 256 / COUT;
    __shared__ int nidx[PPG][K_];
    int t = threadIdx.x;
    int p0 = blockIdx.x * PPG;
    if (t < PPG * K_) nidx[t / K_][t % K_] = idx[(size_t)(p0 + t / K_) * K_ + t % K_];
    __syncthreads();
    int pg = t / COUT;
    int o = t % COUT;
    int p = p0 + pg;
    size_t ybase = (size_t)(p >> 10) << 10;  // batch row base
    float m = -INFINITY;
#pragma unroll
    for (int k = 0; k < K_; ++k)
        m = fmaxf(m, YZ[(ybase + nidx[pg][k]) * NOUT + o]);
    float val = m + YZ[(size_t)p * NOUT + COUT + o];
    val = (val >= 0.f) ? val : 0.2f * val;
    h[(size_t)p * COUT + o] = val;
}

// ---------------------------------------------------------------- two-stage global max pool
// pool1: grid (B, C/64, 16) — each block maxes 64 rows x 64 ch.
template <int C>
__global__ __launch_bounds__(256) void pool1_kernel(const float* __restrict__ h,
                                                    float* __restrict__ partial) {
    __shared__ float red[4][64];
    int bb = blockIdx.x, c0 = blockIdx.y * 64, z = blockIdx.z;
    int lane = threadIdx.x & 63, sl = threadIdx.x >> 6;
    int c = c0 + lane;
    const float* hb = h + (size_t)bb * N_ * C;
    int n0 = z * 64 + sl * 16;
    float mx = -INFINITY;
#pragma unroll
    for (int i = 0; i < 16; ++i) mx = fmaxf(mx, hb[(size_t)(n0 + i) * C + c]);
    red[sl][lane] = mx;
    __syncthreads();
    if (sl == 0) {
        mx = fmaxf(fmaxf(red[0][lane], red[1][lane]), fmaxf(red[2][lane], red[3][lane]));
        partial[((size_t)bb * 16 + z) * C + c] = mx;
    }
}

// pool2: grid (B, C/64) x 64 lanes — reduce 16 partials into f.
template <int C>
__global__ __launch_bounds__(64) void pool2_kernel(const float* __restrict__ partial,
                                                   float* __restrict__ f, int off) {
    int bb = blockIdx.x, c = blockIdx.y * 64 + threadIdx.x;
    float mx = -INFINITY;
#pragma unroll
    for (int z = 0; z < 16; ++z)
        mx = fmaxf(mx, partial[((size_t)bb * 16 + z) * C + c]);
    f[bb * 384 + off + c] = mx;
}

// ---------------------------------------------------------------- FC tail
__global__ __launch_bounds__(128) void fc_tail(
    const float* __restrict__ f, const float* __restrict__ f1w,
    const float* __restrict__ f1b, const float* __restrict__ n1g,
    const float* __restrict__ n1b, const float* __restrict__ n1m,
    const float* __restrict__ n1v, const float* __restrict__ f2w,
    const float* __restrict__ f2b, const float* __restrict__ n2g,
    const float* __restrict__ n2b, const float* __restrict__ n2m,
    const float* __restrict__ n2v, const float* __restrict__ f3w,
    const float* __restrict__ f3b, float* __restrict__ out) {
    __shared__ float fb[384];
    __shared__ float s1[128];
    __shared__ float s2[16];
    int bb = blockIdx.x, t = threadIdx.x;
    for (int j = t; j < 384; j += 128) fb[j] = f[bb * 384 + j];
    __syncthreads();
    float a = f1b[t];
    for (int j = 0; j < 384; ++j) a += f1w[t * 384 + j] * fb[j];
    a = (a - n1m[t]) * (n1g[t] / sqrtf(n1v[t] + EPS_)) + n1b[t];
    s1[t] = fmaxf(a, 0.f);
    __syncthreads();
    if (t < 16) {
        float a2 = f2b[t];
        for (int j = 0; j < 128; ++j) a2 += f2w[t * 128 + j] * s1[j];
        a2 = (a2 - n2m[t]) * (n2g[t] / sqrtf(n2v[t] + EPS_)) + n2b[t];
        s2[t] = fmaxf(a2, 0.f);
    }
    __syncthreads();
    if (t == 0) {
        float a3 = f3b[0];
        for (int j = 0; j < 16; ++j) a3 += f3w[j] * s2[j];
        out[bb] = a3;
    }
}

// ---------------------------------------------------------------- launch
extern "C" void kernel_launch(void* const* d_in, const int* in_sizes, int n_in,
                              void* d_out, int out_size, void* d_ws, size_t ws_size,
                              hipStream_t stream) {
    const float* x = (const float*)d_in[0];
    const float* cw[4] = {(const float*)d_in[1], (const float*)d_in[6],
                          (const float*)d_in[11], (const float*)d_in[16]};
    const float* cg[4] = {(const float*)d_in[2], (const float*)d_in[7],
                          (const float*)d_in[12], (const float*)d_in[17]};
    const float* cb[4] = {(const float*)d_in[3], (const float*)d_in[8],
                          (const float*)d_in[13], (const float*)d_in[18]};
    const float* cm[4] = {(const float*)d_in[4], (const float*)d_in[9],
                          (const float*)d_in[14], (const float*)d_in[19]};
    const float* cv[4] = {(const float*)d_in[5], (const float*)d_in[10],
                          (const float*)d_in[15], (const float*)d_in[20]};
    const float* f1w = (const float*)d_in[21];
    const float* f1b = (const float*)d_in[22];
    const float* n1g = (const float*)d_in[23];
    const float* n1b = (const float*)d_in[24];
    const float* n1m = (const float*)d_in[25];
    const float* n1v = (const float*)d_in[26];
    const float* f2w = (const float*)d_in[27];
    const float* f2b = (const float*)d_in[28];
    const float* n2g = (const float*)d_in[29];
    const float* n2b = (const float*)d_in[30];
    const float* n2m = (const float*)d_in[31];
    const float* n2v = (const float*)d_in[32];
    const float* f3w = (const float*)d_in[33];
    const float* f3b = (const float*)d_in[34];
    float* out = (float*)d_out;

    char* ws = (char*)d_ws;
    size_t off = 0;
    auto alloc = [&](size_t bytes) {
        void* p = ws + off;
        off += (bytes + 255) & ~(size_t)255;
        return p;
    };
    float* sq = (float*)alloc(B_ * N_ * 4);
    int* idx = (int*)alloc((size_t)B_ * N_ * K_ * 4);
    float* h1 = (float*)alloc((size_t)B_ * N_ * 64 * 4);
    float* h2 = (float*)alloc((size_t)B_ * N_ * 64 * 4);
    float* h3 = (float*)alloc((size_t)B_ * N_ * 128 * 4);
    float* h4 = (float*)alloc((size_t)B_ * N_ * 256 * 4);
    float* wd = (float*)alloc(3 * 64 * 4);
    float* wcd = (float*)alloc(3 * 64 * 4);
    float* b2 = (float*)alloc(512 * 4);
    float* f = (float*)alloc(B_ * 384 * 4);
    float* partial = (float*)alloc((size_t)B_ * 16 * 256 * 4);
    unsigned short* Wh = (unsigned short*)alloc((size_t)128 * 512 * 2);
    unsigned short* Wl = (unsigned short*)alloc((size_t)128 * 512 * 2);
    unsigned short* Hh = (unsigned short*)alloc((size_t)B_ * N_ * 128 * 2);
    unsigned short* Hl = (unsigned short*)alloc((size_t)B_ * N_ * 128 * 2);
    // dist (32 MB) and YZ (<=16 MB) have disjoint lifetimes within a layer: overlay.
    float* dist = (float*)alloc((size_t)B_ * N_ * N_ * 4);
    float* YZ = dist;
    (void)ws_size; (void)in_sizes; (void)n_in; (void)out_size;

    const int SELG = B_ * (N_ / 4);  // 1 row/wave, 4 rows/block
    const int SG = (B_ * N_) / 256;
    const int DG = B_ * 64;
    const int GM = B_ * N_;  // points

    // ---- layer 1: 3 -> 64
    split_kernel<3, 32><<<SG, 256, 0, stream>>>(x, Hh, Hl, sq);
    distg_kernel<32><<<DG, 256, 0, stream>>>(Hh, Hl, sq, dist);
    sel_kernel<<<SELG, 256, 0, stream>>>(dist, idx);
    prep_kernel<3, 64><<<1, 256, 0, stream>>>(cw[0], cg[0], cb[0], cm[0], cv[0], wd, wcd, b2);
    y1z1_kernel<<<GM / 4, 256, 0, stream>>>(x, wd, wcd, b2, YZ);
    gathermax_kernel<64><<<GM / 4, 256, 0, stream>>>(YZ, idx, h1);

    // ---- layer 2: 64 -> 64
    split_kernel<64, 64><<<SG, 256, 0, stream>>>(h1, Hh, Hl, sq);
    distg_kernel<64><<<DG, 256, 0, stream>>>(Hh, Hl, sq, dist);
    sel_kernel<<<SELG, 256, 0, stream>>>(dist, idx);
    prep_mfma2<64, 64><<<(64 * 128 + 255) / 256, 256, 0, stream>>>(cw[1], cg[1], cb[1], cm[1], cv[1], Wh, Wl, b2);
    gemmYZ_kernel<64, 128><<<dim3(64, 1), 256, 0, stream>>>(Hh, Hl, Wh, Wl, b2, YZ);
    gathermax_kernel<64><<<GM / 4, 256, 0, stream>>>(YZ, idx, h2);

    // ---- layer 3: 64 -> 128
    split_kernel<64, 64><<<SG, 256, 0, stream>>>(h2, Hh, Hl, sq);
    distg_kernel<64><<<DG, 256, 0, stream>>>(Hh, Hl, sq, dist);
    sel_kernel<<<SELG, 256, 0, stream>>>(dist, idx);
    prep_mfma2<64, 128><<<(64 * 256 + 255) / 256, 256, 0, stream>>>(cw[2], cg[2], cb[2], cm[2], cv[2], Wh, Wl, b2);
    gemmYZ_kernel<64, 256><<<dim3(64, 2), 256, 0, stream>>>(Hh, Hl, Wh, Wl, b2, YZ);
    gathermax_kernel<128><<<GM / 2, 256, 0, stream>>>(YZ, idx, h3);

    // ---- layer 4: 128 -> 256
    split_kernel<128, 128><<<SG, 256, 0, stream>>>(h3, Hh, Hl, sq);
    distg_kernel<128><<<DG, 256, 0, stream>>>(Hh, Hl, sq, dist);
    sel_kernel<<<SELG, 256, 0, stream>>>(dist, idx);
    prep_mfma2<128, 256><<<(128 * 512 + 255) / 256, 256, 0, stream>>>(cw[3], cg[3], cb[3], cm[3], cv[3], Wh, Wl, b2);
    gemmYZ_kernel<128, 512><<<dim3(64, 4), 256, 0, stream>>>(Hh, Hl, Wh, Wl, b2, YZ);
    gathermax_kernel<256><<<GM, 256, 0, stream>>>(YZ, idx, h4);

    // ---- pooling + FC tail
    pool1_kernel<128><<<dim3(B_, 2, 16), 256, 0, stream>>>(h3, partial);
    pool2_kernel<128><<<dim3(B_, 2), 64, 0, stream>>>(partial, f, 0);
    pool1_kernel<256><<<dim3(B_, 4, 16), 256, 0, stream>>>(h4, partial);
    pool2_kernel<256><<<dim3(B_, 4), 64, 0, stream>>>(partial, f, 128);
    fc_tail<<<B_, 128, 0, stream>>>(f, f1w, f1b, n1g, n1b, n1m, n1v, f2w, f2b, n2g, n2b,
                                    n2m, n2v, f3w, f3b, out);
}

// Round 11
// 297.337 us; speedup vs baseline: 5.1906x; 1.1598x over previous
//
#include <hip/hip_runtime.h>
#include <math.h>

constexpr int B_ = 8;
constexpr int N_ = 1024;
constexpr int K_ = 20;
constexpr float EPS_ = 1e-5f;

typedef __attribute__((ext_vector_type(8))) short short8;
typedef __attribute__((ext_vector_type(4))) float f32x4;
typedef unsigned long long u64;

// hi/lo bf16 split (RNE both halves)
__device__ __forceinline__ void bf16split(float x, unsigned short& h, unsigned short& l) {
    unsigned u = __float_as_uint(x);
    unsigned rh = (u + 0x7FFFu + ((u >> 16) & 1u)) >> 16;
    h = (unsigned short)rh;
    float lof = x - __uint_as_float(rh << 16);
    unsigned ul = __float_as_uint(lof);
    l = (unsigned short)((ul + 0x7FFFu + ((ul >> 16) & 1u)) >> 16);
}

// ---------------------------------------------------------------- split + sq (layer-1 x only)
template <int C, int CP>
__global__ __launch_bounds__(256) void split_kernel(const float* __restrict__ h,
                                                    unsigned short* __restrict__ Hh,
                                                    unsigned short* __restrict__ Hl,
                                                    float* __restrict__ sq) {
    int p = blockIdx.x * 256 + threadIdx.x;
    if (p >= B_ * N_) return;
    const float* r = h + (size_t)p * C;
    unsigned short hb[CP], lb[CP];
    float s = 0.f;
#pragma unroll
    for (int c = 0; c < C; ++c) {
        float v = r[c];
        s += v * v;
        bf16split(v, hb[c], lb[c]);
    }
#pragma unroll
    for (int c = C; c < CP; ++c) { hb[c] = 0; lb[c] = 0; }
    sq[p] = s;
#pragma unroll
    for (int i = 0; i < CP / 8; ++i) {
        *(short8*)&Hh[(size_t)p * CP + 8 * i] = *(const short8*)&hb[8 * i];
        *(short8*)&Hl[(size_t)p * CP + 8 * i] = *(const short8*)&lb[8 * i];
    }
}

// ---------------------------------------------------------------- distance GEMM body
template <int CP>
__device__ __forceinline__ void distg_body(unsigned short* smem,
                                           const unsigned short* __restrict__ Hh,
                                           const unsigned short* __restrict__ Hl,
                                           const float* __restrict__ sq,
                                           float* __restrict__ dist, int bid) {
    constexpr int KC = CP / 32;
    constexpr int STR = 40;
    unsigned short* As = smem;                 // 2 planes x 128*STR
    unsigned short* Bs = smem + 2 * 128 * STR;
    int t = threadIdx.x;
    int bb = bid >> 6;
    int r0 = ((bid >> 3) & 7) * 128;
    int c0 = (bid & 7) * 128;
    size_t base = (size_t)bb * N_;
    int lane = t & 63, wave = t >> 6, quad = lane >> 4, nl = lane & 15;
    int wm = wave >> 1, wn = wave & 1;

    f32x4 acc[4][4];
#pragma unroll
    for (int mt = 0; mt < 4; ++mt)
#pragma unroll
        for (int nt = 0; nt < 4; ++nt) acc[mt][nt] = (f32x4){0.f, 0.f, 0.f, 0.f};

    for (int kc = 0; kc < KC; ++kc) {
        if (kc) __syncthreads();
#pragma unroll
        for (int i = 0; i < 2; ++i) {
            int cid = t + i * 256;
            int row = cid >> 2, j = cid & 3;
            size_t asrc = (base + r0 + row) * CP + kc * 32 + 8 * j;
            size_t bsrc = (base + c0 + row) * CP + kc * 32 + 8 * j;
            int dst = row * STR + 8 * j;
            *(short8*)&As[dst] = *(const short8*)&Hh[asrc];
            *(short8*)&As[128 * STR + dst] = *(const short8*)&Hl[asrc];
            *(short8*)&Bs[dst] = *(const short8*)&Hh[bsrc];
            *(short8*)&Bs[128 * STR + dst] = *(const short8*)&Hl[bsrc];
        }
        __syncthreads();
        short8 ah[4], al[4];
#pragma unroll
        for (int mt = 0; mt < 4; ++mt) {
            int off = (wm * 64 + mt * 16 + nl) * STR + quad * 8;
            ah[mt] = *(const short8*)&As[off];
            al[mt] = *(const short8*)&As[128 * STR + off];
        }
#pragma unroll
        for (int nt = 0; nt < 4; ++nt) {
            int off = (wn * 64 + nt * 16 + nl) * STR + quad * 8;
            short8 bh = *(const short8*)&Bs[off];
            short8 bl = *(const short8*)&Bs[128 * STR + off];
#pragma unroll
            for (int mt = 0; mt < 4; ++mt) {
                acc[mt][nt] = __builtin_amdgcn_mfma_f32_16x16x32_bf16(ah[mt], bh, acc[mt][nt], 0, 0, 0);
                acc[mt][nt] = __builtin_amdgcn_mfma_f32_16x16x32_bf16(ah[mt], bl, acc[mt][nt], 0, 0, 0);
                acc[mt][nt] = __builtin_amdgcn_mfma_f32_16x16x32_bf16(al[mt], bh, acc[mt][nt], 0, 0, 0);
            }
        }
    }
    float sqc[4];
#pragma unroll
    for (int nt = 0; nt < 4; ++nt) sqc[nt] = sq[base + c0 + wn * 64 + nt * 16 + nl];
    float* dbase = dist + (size_t)bb * N_ * N_;
#pragma unroll
    for (int mt = 0; mt < 4; ++mt) {
#pragma unroll
        for (int r = 0; r < 4; ++r) {
            int row = r0 + wm * 64 + mt * 16 + quad * 4 + r;
            float sqr = sq[base + row];
#pragma unroll
            for (int nt = 0; nt < 4; ++nt)
                dbase[(size_t)row * N_ + c0 + wn * 64 + nt * 16 + nl] =
                    2.f * acc[mt][nt][r] - sqr - sqc[nt];
        }
    }
}

// ---------------------------------------------------------------- Y|Z GEMM body
template <int CP, int NOUT>
__device__ __forceinline__ void gemmyz_body(unsigned short* smem,
                                            const unsigned short* __restrict__ Hh,
                                            const unsigned short* __restrict__ Hl,
                                            const unsigned short* __restrict__ Wh,
                                            const unsigned short* __restrict__ Wl,
                                            const float* __restrict__ bias2,
                                            float* __restrict__ YZ, int yb) {
    constexpr int KC = CP / 32;
    constexpr int NTt = NOUT / 16;
    constexpr int STR = 40;
    unsigned short* As = smem;  // 2 planes x 128*STR
    int t = threadIdx.x;
    int m0 = (yb & 63) * 128;
    int n0 = (yb >> 6) * 128;
    int lane = t & 63, wave = t >> 6, quad = lane >> 4, nl = lane & 15;
    int wm = wave >> 1, wn = wave & 1;

    f32x4 acc[4][4];
#pragma unroll
    for (int mt = 0; mt < 4; ++mt)
#pragma unroll
        for (int nt = 0; nt < 4; ++nt) acc[mt][nt] = (f32x4){0.f, 0.f, 0.f, 0.f};

    for (int kc = 0; kc < KC; ++kc) {
        if (kc) __syncthreads();
#pragma unroll
        for (int i = 0; i < 2; ++i) {
            int cid = t + i * 256;
            int row = cid >> 2, j = cid & 3;
            size_t src = ((size_t)(m0 + row)) * CP + kc * 32 + 8 * j;
            int dst = row * STR + 8 * j;
            *(short8*)&As[dst] = *(const short8*)&Hh[src];
            *(short8*)&As[128 * STR + dst] = *(const short8*)&Hl[src];
        }
        __syncthreads();
        short8 ah[4], al[4];
#pragma unroll
        for (int mt = 0; mt < 4; ++mt) {
            int off = (wm * 64 + mt * 16 + nl) * STR + quad * 8;
            ah[mt] = *(const short8*)&As[off];
            al[mt] = *(const short8*)&As[128 * STR + off];
        }
#pragma unroll
        for (int nt = 0; nt < 4; ++nt) {
            int ntg = (n0 >> 4) + wn * 4 + nt;
            size_t bpos = ((size_t)(kc * NTt + ntg) * 64 + lane) * 8;
            short8 bh = *(const short8*)&Wh[bpos];
            short8 bl = *(const short8*)&Wl[bpos];
#pragma unroll
            for (int mt = 0; mt < 4; ++mt) {
                acc[mt][nt] = __builtin_amdgcn_mfma_f32_16x16x32_bf16(ah[mt], bh, acc[mt][nt], 0, 0, 0);
                acc[mt][nt] = __builtin_amdgcn_mfma_f32_16x16x32_bf16(ah[mt], bl, acc[mt][nt], 0, 0, 0);
                acc[mt][nt] = __builtin_amdgcn_mfma_f32_16x16x32_bf16(al[mt], bh, acc[mt][nt], 0, 0, 0);
            }
        }
    }
#pragma unroll
    for (int nt = 0; nt < 4; ++nt) {
        int col = n0 + wn * 64 + nt * 16 + nl;
        float bv = bias2[col];
#pragma unroll
        for (int mt = 0; mt < 4; ++mt) {
#pragma unroll
            for (int r = 0; r < 4; ++r) {
                int row = m0 + wm * 64 + mt * 16 + quad * 4 + r;
                YZ[(size_t)row * NOUT + col] = acc[mt][nt][r] + bv;
            }
        }
    }
}

// ---------------------------------------------------------------- kernels wrapping the bodies
template <int CP>
__global__ __launch_bounds__(256) void distg_kernel(const unsigned short* __restrict__ Hh,
                                                    const unsigned short* __restrict__ Hl,
                                                    const float* __restrict__ sq,
                                                    float* __restrict__ dist) {
    __shared__ unsigned short smem[4 * 128 * 40];
    distg_body<CP>(smem, Hh, Hl, sq, dist, blockIdx.x);
}

// merged: blocks [0,512) compute dist tiles; blocks [512, 512+64*NOUT/128) compute YZ.
template <int CP, int NOUT>
__global__ __launch_bounds__(256) void distyz_kernel(const unsigned short* __restrict__ Hh,
                                                     const unsigned short* __restrict__ Hl,
                                                     const float* __restrict__ sq,
                                                     float* __restrict__ dist,
                                                     const unsigned short* __restrict__ Wh,
                                                     const unsigned short* __restrict__ Wl,
                                                     const float* __restrict__ bias2,
                                                     float* __restrict__ YZ) {
    __shared__ unsigned short smem[4 * 128 * 40];
    if (blockIdx.x < 512)
        distg_body<CP>(smem, Hh, Hl, sq, dist, blockIdx.x);
    else
        gemmyz_body<CP, NOUT>(smem, Hh, Hl, Wh, Wl, bias2, YZ, blockIdx.x - 512);
}

// ---------------------------------------------------------------- top-20 select
__device__ __forceinline__ unsigned int fkey(float f) {
    unsigned int u = __float_as_uint(f);
    return (u & 0x80000000u) ? ~u : (u | 0x80000000u);
}

__device__ __forceinline__ u64 tree16(const u64* v) {
    u64 t0[8];
#pragma unroll
    for (int s = 0; s < 8; ++s) t0[s] = v[2 * s] > v[2 * s + 1] ? v[2 * s] : v[2 * s + 1];
#pragma unroll
    for (int s = 0; s < 4; ++s) t0[s] = t0[2 * s] > t0[2 * s + 1] ? t0[2 * s] : t0[2 * s + 1];
    t0[0] = t0[0] > t0[1] ? t0[0] : t0[1];
    t0[2] = t0[2] > t0[3] ? t0[2] : t0[3];
    return t0[0] > t0[2] ? t0[0] : t0[2];
}

__device__ __forceinline__ u64 wave_sort_desc(u64 v, int lane) {
#pragma unroll
    for (int k2 = 2; k2 <= 64; k2 <<= 1) {
#pragma unroll
        for (int j = k2 >> 1; j > 0; j >>= 1) {
            u64 o = __shfl_xor(v, j);
            bool desc = ((lane & k2) == 0);
            bool lower = ((lane & j) == 0);
            u64 mx = v > o ? v : o;
            u64 mn = v > o ? o : v;
            v = (desc == lower) ? mx : mn;
        }
    }
    return v;
}

// One row per wave.  Threshold-filter top-20 (exact set; fallback exact loop).
__global__ __launch_bounds__(256) void sel_kernel(const float* __restrict__ dist,
                                                  int* __restrict__ idx) {
    __shared__ u64 cand[4][64];
    int t = threadIdx.x;
    int wave = t >> 6, lane = t & 63;
    int gr = blockIdx.x * 4 + wave;
    const float* d = dist + (size_t)gr * N_;
    int* op = idx + (size_t)gr * K_;
    int c0 = lane * 16;

    u64 kk[16];
#pragma unroll
    for (int i = 0; i < 4; ++i) {
        float4 a = *(const float4*)&d[c0 + 4 * i];
        float av[4] = {a.x, a.y, a.z, a.w};
#pragma unroll
        for (int e = 0; e < 4; ++e) {
            int c = c0 + 4 * i + e;
            kk[4 * i + e] = ((u64)fkey(av[e]) << 32) | (unsigned int)(~c);
        }
    }

    u64 lm = tree16(kk);
    u64 lms = wave_sort_desc(lm, lane);
    u64 tau = __shfl(lms, 19);

    int cnt = 0;
#pragma unroll
    for (int i = 0; i < 16; ++i) cnt += (kk[i] >= tau) ? 1 : 0;
    int incl = cnt;
#pragma unroll
    for (int dd = 1; dd < 64; dd <<= 1) {
        int n = __shfl_up(incl, dd);
        if (lane >= dd) incl += n;
    }
    int excl = incl - cnt;
    int Ctot = __shfl(incl, 63);

    if (Ctot <= 64) {
        cand[wave][lane] = 0ull;
        __builtin_amdgcn_wave_barrier();
        int pos = excl;
#pragma unroll
        for (int i = 0; i < 16; ++i) {
            if (kk[i] >= tau) { cand[wave][pos] = kk[i]; ++pos; }
        }
        __builtin_amdgcn_wave_barrier();
        u64 c = cand[wave][lane];
        c = wave_sort_desc(c, lane);
        if (lane < K_) op[lane] = (int)(~(unsigned int)c);
    } else {
        for (int it = 0; it < K_; ++it) {
            u64 m = tree16(kk);
#pragma unroll
            for (int off = 32; off; off >>= 1) {
                u64 o = __shfl_xor(m, off);
                m = o > m ? o : m;
            }
            if (lane == 0) op[it] = (int)(~(unsigned int)m);
#pragma unroll
            for (int j = 0; j < 16; ++j) kk[j] = (kk[j] == m) ? 0ull : kk[j];
        }
    }
}

// ---------------------------------------------------------------- all-layer weight prep
__device__ __forceinline__ void prep_mfma2_elem(int e, int CIN, int COUT_,
                                                const float* w, const float* g,
                                                const float* bb, const float* m,
                                                const float* v,
                                                unsigned short* Wh, unsigned short* Wl,
                                                float* bias2) {
    int NOUT = 2 * COUT_;
    int NT = NOUT / 16;
    int n = e % NOUT, k = e / NOUT;
    int o = (n < COUT_) ? n : n - COUT_;
    float a = g[o] / sqrtf(v[o] + EPS_);
    float wv = (n < COUT_) ? a * w[o * 2 * CIN + k]
                           : a * (w[o * 2 * CIN + CIN + k] - w[o * 2 * CIN + k]);
    unsigned short hs, ls;
    bf16split(wv, hs, ls);
    int kc = k >> 5, ko = k & 31, quad = ko >> 3, j = ko & 7;
    int nt = n >> 4, nl = n & 15;
    size_t pos = ((size_t)(kc * NT + nt) * 64 + quad * 16 + nl) * 8 + j;
    Wh[pos] = hs;
    Wl[pos] = ls;
    if (k == 0) bias2[n] = (n < COUT_) ? 0.f : (bb[o] - m[o] * a);
}

__global__ __launch_bounds__(256) void prep_all(
    const float* __restrict__ w1, const float* __restrict__ g1, const float* __restrict__ bb1,
    const float* __restrict__ m1, const float* __restrict__ v1,
    const float* __restrict__ w2, const float* __restrict__ g2, const float* __restrict__ bb2,
    const float* __restrict__ m2, const float* __restrict__ v2,
    const float* __restrict__ w3, const float* __restrict__ g3, const float* __restrict__ bb3,
    const float* __restrict__ m3, const float* __restrict__ v3,
    const float* __restrict__ w4, const float* __restrict__ g4, const float* __restrict__ bb4,
    const float* __restrict__ m4, const float* __restrict__ v4,
    float* __restrict__ wd, float* __restrict__ wcd, float* __restrict__ bias1,
    unsigned short* __restrict__ Wh2, unsigned short* __restrict__ Wl2, float* __restrict__ b22,
    unsigned short* __restrict__ Wh3, unsigned short* __restrict__ Wl3, float* __restrict__ b23,
    unsigned short* __restrict__ Wh4, unsigned short* __restrict__ Wl4, float* __restrict__ b24) {
    int e = blockIdx.x * 256 + threadIdx.x;
    if (e < 192) {                       // L1 fp32 prep (i*64+o)
        int o = e % 64, i = e / 64;
        float a = g1[o] / sqrtf(v1[o] + EPS_);
        float wdv = w1[o * 6 + i];
        wd[e] = a * wdv;
        wcd[e] = a * (w1[o * 6 + 3 + i] - wdv);
        if (i == 0) bias1[o] = bb1[o] - m1[o] * a;
    } else if (e < 192 + 8192) {
        prep_mfma2_elem(e - 192, 64, 64, w2, g2, bb2, m2, v2, Wh2, Wl2, b22);
    } else if (e < 192 + 8192 + 16384) {
        prep_mfma2_elem(e - 8384, 64, 128, w3, g3, bb3, m3, v3, Wh3, Wl3, b23);
    } else if (e < 192 + 8192 + 16384 + 65536) {
        prep_mfma2_elem(e - 24768, 128, 256, w4, g4, bb4, m4, v4, Wh4, Wl4, b24);
    }
}

// ---------------------------------------------------------------- L1 Y|Z (fp32, CIN=3)
__global__ __launch_bounds__(256) void y1z1_kernel(const float* __restrict__ x,
                                                   const float* __restrict__ wdT,
                                                   const float* __restrict__ wcdT,
                                                   const float* __restrict__ bias2,
                                                   float* __restrict__ YZ) {
    int t = threadIdx.x;
    int p = blockIdx.x * 4 + (t >> 6);
    int o = t & 63;
    float x0 = x[3 * p], x1 = x[3 * p + 1], x2 = x[3 * p + 2];
    float y = x0 * wdT[o] + x1 * wdT[64 + o] + x2 * wdT[128 + o];
    float z = bias2[o] + x0 * wcdT[o] + x1 * wcdT[64 + o] + x2 * wcdT[128 + o];
    YZ[(size_t)p * 128 + o] = y;
    YZ[(size_t)p * 128 + 64 + o] = z;
}

// ---------------------------------------------------------------- gather+max+lrelu fused with split
// Writes next layer's Hh/Hl (bf16 hi/lo) + sq; optionally raw h (for pool input).
template <int COUT, bool WRITE_H>
__global__ __launch_bounds__(256) void gmxf_kernel(const float* __restrict__ YZ,
                                                   const int* __restrict__ idx,
                                                   unsigned short* __restrict__ Hh,
                                                   unsigned short* __restrict__ Hl,
                                                   float* __restrict__ sq,
                                                   float* __restrict__ h) {
    constexpr int NOUT = 2 * COUT;
    constexpr int PPG = 256 / COUT;
    __shared__ int nidx[PPG][K_];
    __shared__ float part[4];
    int t = threadIdx.x;
    int p0 = blockIdx.x * PPG;
    if (t < PPG * K_) nidx[t / K_][t % K_] = idx[(size_t)(p0 + t / K_) * K_ + t % K_];
    __syncthreads();
    int pg = t / COUT, o = t % COUT, p = p0 + pg;
    size_t ybase = (size_t)(p >> 10) << 10;
    float m = -INFINITY;
#pragma unroll
    for (int k = 0; k < K_; ++k)
        m = fmaxf(m, YZ[(ybase + nidx[pg][k]) * NOUT + o]);
    float val = m + YZ[(size_t)p * NOUT + COUT + o];
    val = (val >= 0.f) ? val : 0.2f * val;
    if constexpr (WRITE_H) h[(size_t)p * COUT + o] = val;
    unsigned short hi, lo;
    bf16split(val, hi, lo);
    Hh[(size_t)p * COUT + o] = hi;
    Hl[(size_t)p * COUT + o] = lo;
    // sq = sum over channels of val^2 (wave butterfly + cross-wave LDS combine)
    float s = val * val;
#pragma unroll
    for (int d = 32; d; d >>= 1) s += __shfl_xor(s, d);
    int wave = t >> 6, lane = t & 63;
    if (lane == 0) part[wave] = s;
    __syncthreads();
    if (t < PPG) {
        constexpr int WPP = COUT / 64;
        float tot = 0.f;
#pragma unroll
        for (int w2 = 0; w2 < WPP; ++w2) tot += part[t * WPP + w2];
        sq[p0 + t] = tot;
    }
}

// plain gathermax (final layer: h4 only)
template <int COUT>
__global__ __launch_bounds__(256) void gathermax_kernel(const float* __restrict__ YZ,
                                                        const int* __restrict__ idx,
                                                        float* __restrict__ h) {
    constexpr int NOUT = 2 * COUT;
    constexpr int PPG = 256 / COUT;
    __shared__ int nidx[PPG][K_];
    int t = threadIdx.x;
    int p0 = blockIdx.x * PPG;
    if (t < PPG * K_) nidx[t / K_][t % K_] = idx[(size_t)(p0 + t / K_) * K_ + t % K_];
    __syncthreads();
    int pg = t / COUT;
    int o = t % COUT;
    int p = p0 + pg;
    size_t ybase = (size_t)(p >> 10) << 10;
    float m = -INFINITY;
#pragma unroll
    for (int k = 0; k < K_; ++k)
        m = fmaxf(m, YZ[(ybase + nidx[pg][k]) * NOUT + o]);
    float val = m + YZ[(size_t)p * NOUT + COUT + o];
    val = (val >= 0.f) ? val : 0.2f * val;
    h[(size_t)p * COUT + o] = val;
}

// ---------------------------------------------------------------- two-stage global max pool
template <int C>
__global__ __launch_bounds__(256) void pool1_kernel(const float* __restrict__ h,
                                                    float* __restrict__ partial) {
    __shared__ float red[4][64];
    int bb = blockIdx.x, c0 = blockIdx.y * 64, z = blockIdx.z;
    int lane = threadIdx.x & 63, sl = threadIdx.x >> 6;
    int c = c0 + lane;
    const float* hb = h + (size_t)bb * N_ * C;
    int n0 = z * 64 + sl * 16;
    float mx = -INFINITY;
#pragma unroll
    for (int i = 0; i < 16; ++i) mx = fmaxf(mx, hb[(size_t)(n0 + i) * C + c]);
    red[sl][lane] = mx;
    __syncthreads();
    if (sl == 0) {
        mx = fmaxf(fmaxf(red[0][lane], red[1][lane]), fmaxf(red[2][lane], red[3][lane]));
        partial[((size_t)bb * 16 + z) * C + c] = mx;
    }
}

template <int C>
__global__ __launch_bounds__(64) void pool2_kernel(const float* __restrict__ partial,
                                                   float* __restrict__ f, int off) {
    int bb = blockIdx.x, c = blockIdx.y * 64 + threadIdx.x;
    float mx = -INFINITY;
#pragma unroll
    for (int z = 0; z < 16; ++z)
        mx = fmaxf(mx, partial[((size_t)bb * 16 + z) * C + c]);
    f[bb * 384 + off + c] = mx;
}

// ---------------------------------------------------------------- FC tail
__global__ __launch_bounds__(128) void fc_tail(
    const float* __restrict__ f, const float* __restrict__ f1w,
    const float* __restrict__ f1b, const float* __restrict__ n1g,
    const float* __restrict__ n1b, const float* __restrict__ n1m,
    const float* __restrict__ n1v, const float* __restrict__ f2w,
    const float* __restrict__ f2b, const float* __restrict__ n2g,
    const float* __restrict__ n2b, const float* __restrict__ n2m,
    const float* __restrict__ n2v, const float* __restrict__ f3w,
    const float* __restrict__ f3b, float* __restrict__ out) {
    __shared__ float fb[384];
    __shared__ float s1[128];
    __shared__ float s2[16];
    int bb = blockIdx.x, t = threadIdx.x;
    for (int j = t; j < 384; j += 128) fb[j] = f[bb * 384 + j];
    __syncthreads();
    float a = f1b[t];
    for (int j = 0; j < 384; ++j) a += f1w[t * 384 + j] * fb[j];
    a = (a - n1m[t]) * (n1g[t] / sqrtf(n1v[t] + EPS_)) + n1b[t];
    s1[t] = fmaxf(a, 0.f);
    __syncthreads();
    if (t < 16) {
        float a2 = f2b[t];
        for (int j = 0; j < 128; ++j) a2 += f2w[t * 128 + j] * s1[j];
        a2 = (a2 - n2m[t]) * (n2g[t] / sqrtf(n2v[t] + EPS_)) + n2b[t];
        s2[t] = fmaxf(a2, 0.f);
    }
    __syncthreads();
    if (t == 0) {
        float a3 = f3b[0];
        for (int j = 0; j < 16; ++j) a3 += f3w[j] * s2[j];
        out[bb] = a3;
    }
}

// ---------------------------------------------------------------- launch
extern "C" void kernel_launch(void* const* d_in, const int* in_sizes, int n_in,
                              void* d_out, int out_size, void* d_ws, size_t ws_size,
                              hipStream_t stream) {
    const float* x = (const float*)d_in[0];
    const float* cw[4] = {(const float*)d_in[1], (const float*)d_in[6],
                          (const float*)d_in[11], (const float*)d_in[16]};
    const float* cg[4] = {(const float*)d_in[2], (const float*)d_in[7],
                          (const float*)d_in[12], (const float*)d_in[17]};
    const float* cb[4] = {(const float*)d_in[3], (const float*)d_in[8],
                          (const float*)d_in[13], (const float*)d_in[18]};
    const float* cm[4] = {(const float*)d_in[4], (const float*)d_in[9],
                          (const float*)d_in[14], (const float*)d_in[19]};
    const float* cv[4] = {(const float*)d_in[5], (const float*)d_in[10],
                          (const float*)d_in[15], (const float*)d_in[20]};
    const float* f1w = (const float*)d_in[21];
    const float* f1b = (const float*)d_in[22];
    const float* n1g = (const float*)d_in[23];
    const float* n1b = (const float*)d_in[24];
    const float* n1m = (const float*)d_in[25];
    const float* n1v = (const float*)d_in[26];
    const float* f2w = (const float*)d_in[27];
    const float* f2b = (const float*)d_in[28];
    const float* n2g = (const float*)d_in[29];
    const float* n2b = (const float*)d_in[30];
    const float* n2m = (const float*)d_in[31];
    const float* n2v = (const float*)d_in[32];
    const float* f3w = (const float*)d_in[33];
    const float* f3b = (const float*)d_in[34];
    float* out = (float*)d_out;

    char* ws = (char*)d_ws;
    size_t off = 0;
    auto alloc = [&](size_t bytes) {
        void* p = ws + off;
        off += (bytes + 255) & ~(size_t)255;
        return p;
    };
    float* sq = (float*)alloc(B_ * N_ * 4);
    int* idx = (int*)alloc((size_t)B_ * N_ * K_ * 4);
    float* h3 = (float*)alloc((size_t)B_ * N_ * 128 * 4);
    float* h4 = (float*)alloc((size_t)B_ * N_ * 256 * 4);
    float* wd = (float*)alloc(3 * 64 * 4);
    float* wcd = (float*)alloc(3 * 64 * 4);
    float* bias1 = (float*)alloc(64 * 4);
    float* b22 = (float*)alloc(128 * 4);
    float* b23 = (float*)alloc(256 * 4);
    float* b24 = (float*)alloc(512 * 4);
    float* f = (float*)alloc(B_ * 384 * 4);
    float* partial = (float*)alloc((size_t)B_ * 16 * 256 * 4);
    unsigned short* Wh2 = (unsigned short*)alloc(64 * 128 * 2);
    unsigned short* Wl2 = (unsigned short*)alloc(64 * 128 * 2);
    unsigned short* Wh3 = (unsigned short*)alloc(64 * 256 * 2);
    unsigned short* Wl3 = (unsigned short*)alloc(64 * 256 * 2);
    unsigned short* Wh4 = (unsigned short*)alloc(128 * 512 * 2);
    unsigned short* Wl4 = (unsigned short*)alloc(128 * 512 * 2);
    unsigned short* Hh = (unsigned short*)alloc((size_t)B_ * N_ * 128 * 2);
    unsigned short* Hl = (unsigned short*)alloc((size_t)B_ * N_ * 128 * 2);
    float* dist = (float*)alloc((size_t)B_ * N_ * N_ * 4);
    float* YZ = (float*)alloc((size_t)B_ * N_ * 512 * 4);  // separate: distyz writes both
    (void)ws_size; (void)in_sizes; (void)n_in; (void)out_size;

    const int SELG = B_ * (N_ / 4);
    const int SG = (B_ * N_) / 256;
    const int GM = B_ * N_;

    // ---- all weight prep (data-independent)
    prep_all<<<(192 + 8192 + 16384 + 65536 + 255) / 256, 256, 0, stream>>>(
        cw[0], cg[0], cb[0], cm[0], cv[0], cw[1], cg[1], cb[1], cm[1], cv[1],
        cw[2], cg[2], cb[2], cm[2], cv[2], cw[3], cg[3], cb[3], cm[3], cv[3],
        wd, wcd, bias1, Wh2, Wl2, b22, Wh3, Wl3, b23, Wh4, Wl4, b24);

    // ---- layer 1: 3 -> 64
    split_kernel<3, 32><<<SG, 256, 0, stream>>>(x, Hh, Hl, sq);
    distg_kernel<32><<<B_ * 64, 256, 0, stream>>>(Hh, Hl, sq, dist);
    sel_kernel<<<SELG, 256, 0, stream>>>(dist, idx);
    y1z1_kernel<<<GM / 4, 256, 0, stream>>>(x, wd, wcd, bias1, YZ);
    gmxf_kernel<64, false><<<GM / 4, 256, 0, stream>>>(YZ, idx, Hh, Hl, sq, nullptr);

    // ---- layer 2: 64 -> 64 (dist + YZ in one launch)
    distyz_kernel<64, 128><<<512 + 64, 256, 0, stream>>>(Hh, Hl, sq, dist, Wh2, Wl2, b22, YZ);
    sel_kernel<<<SELG, 256, 0, stream>>>(dist, idx);
    gmxf_kernel<64, false><<<GM / 4, 256, 0, stream>>>(YZ, idx, Hh, Hl, sq, nullptr);

    // ---- layer 3: 64 -> 128
    distyz_kernel<64, 256><<<512 + 128, 256, 0, stream>>>(Hh, Hl, sq, dist, Wh3, Wl3, b23, YZ);
    sel_kernel<<<SELG, 256, 0, stream>>>(dist, idx);
    gmxf_kernel<128, true><<<GM / 2, 256, 0, stream>>>(YZ, idx, Hh, Hl, sq, h3);

    // ---- layer 4: 128 -> 256
    distyz_kernel<128, 512><<<512 + 256, 256, 0, stream>>>(Hh, Hl, sq, dist, Wh4, Wl4, b24, YZ);
    sel_kernel<<<SELG, 256, 0, stream>>>(dist, idx);
    gathermax_kernel<256><<<GM, 256, 0, stream>>>(YZ, idx, h4);

    // ---- pooling + FC tail
    pool1_kernel<128><<<dim3(B_, 2, 16), 256, 0, stream>>>(h3, partial);
    pool2_kernel<128><<<dim3(B_, 2), 64, 0, stream>>>(partial, f, 0);
    pool1_kernel<256><<<dim3(B_, 4, 16), 256, 0, stream>>>(h4, partial);
    pool2_kernel<256><<<dim3(B_, 4), 64, 0, stream>>>(partial, f, 128);
    fc_tail<<<B_, 128, 0, stream>>>(f, f1w, f1b, n1g, n1b, n1m, n1v, f2w, f2b, n2g, n2b,
                                    n2m, n2v, f3w, f3b, out);
}

// Round 12
// 284.834 us; speedup vs baseline: 5.4185x; 1.0439x over previous
//
#include <hip/hip_runtime.h>
#include <math.h>

constexpr int B_ = 8;
constexpr int N_ = 1024;
constexpr int K_ = 20;
constexpr float EPS_ = 1e-5f;

typedef __attribute__((ext_vector_type(8))) short short8;
typedef __attribute__((ext_vector_type(4))) float f32x4;
typedef unsigned long long u64;

// hi/lo bf16 split (RNE both halves)
__device__ __forceinline__ void bf16split(float x, unsigned short& h, unsigned short& l) {
    unsigned u = __float_as_uint(x);
    unsigned rh = (u + 0x7FFFu + ((u >> 16) & 1u)) >> 16;
    h = (unsigned short)rh;
    float lof = x - __uint_as_float(rh << 16);
    unsigned ul = __float_as_uint(lof);
    l = (unsigned short)((ul + 0x7FFFu + ((ul >> 16) & 1u)) >> 16);
}

// ---------------------------------------------------------------- distance GEMM body
template <int CP>
__device__ __forceinline__ void distg_body(unsigned short* smem,
                                           const unsigned short* __restrict__ Hh,
                                           const unsigned short* __restrict__ Hl,
                                           const float* __restrict__ sq,
                                           float* __restrict__ dist, int bid) {
    constexpr int KC = CP / 32;
    constexpr int STR = 40;
    unsigned short* As = smem;
    unsigned short* Bs = smem + 2 * 128 * STR;
    int t = threadIdx.x;
    int bb = bid >> 6;
    int r0 = ((bid >> 3) & 7) * 128;
    int c0 = (bid & 7) * 128;
    size_t base = (size_t)bb * N_;
    int lane = t & 63, wave = t >> 6, quad = lane >> 4, nl = lane & 15;
    int wm = wave >> 1, wn = wave & 1;

    f32x4 acc[4][4];
#pragma unroll
    for (int mt = 0; mt < 4; ++mt)
#pragma unroll
        for (int nt = 0; nt < 4; ++nt) acc[mt][nt] = (f32x4){0.f, 0.f, 0.f, 0.f};

    for (int kc = 0; kc < KC; ++kc) {
        if (kc) __syncthreads();
#pragma unroll
        for (int i = 0; i < 2; ++i) {
            int cid = t + i * 256;
            int row = cid >> 2, j = cid & 3;
            size_t asrc = (base + r0 + row) * CP + kc * 32 + 8 * j;
            size_t bsrc = (base + c0 + row) * CP + kc * 32 + 8 * j;
            int dst = row * STR + 8 * j;
            *(short8*)&As[dst] = *(const short8*)&Hh[asrc];
            *(short8*)&As[128 * STR + dst] = *(const short8*)&Hl[asrc];
            *(short8*)&Bs[dst] = *(const short8*)&Hh[bsrc];
            *(short8*)&Bs[128 * STR + dst] = *(const short8*)&Hl[bsrc];
        }
        __syncthreads();
        short8 ah[4], al[4];
#pragma unroll
        for (int mt = 0; mt < 4; ++mt) {
            int off = (wm * 64 + mt * 16 + nl) * STR + quad * 8;
            ah[mt] = *(const short8*)&As[off];
            al[mt] = *(const short8*)&As[128 * STR + off];
        }
#pragma unroll
        for (int nt = 0; nt < 4; ++nt) {
            int off = (wn * 64 + nt * 16 + nl) * STR + quad * 8;
            short8 bh = *(const short8*)&Bs[off];
            short8 bl = *(const short8*)&Bs[128 * STR + off];
#pragma unroll
            for (int mt = 0; mt < 4; ++mt) {
                acc[mt][nt] = __builtin_amdgcn_mfma_f32_16x16x32_bf16(ah[mt], bh, acc[mt][nt], 0, 0, 0);
                acc[mt][nt] = __builtin_amdgcn_mfma_f32_16x16x32_bf16(ah[mt], bl, acc[mt][nt], 0, 0, 0);
                acc[mt][nt] = __builtin_amdgcn_mfma_f32_16x16x32_bf16(al[mt], bh, acc[mt][nt], 0, 0, 0);
            }
        }
    }
    float sqc[4];
#pragma unroll
    for (int nt = 0; nt < 4; ++nt) sqc[nt] = sq[base + c0 + wn * 64 + nt * 16 + nl];
    float* dbase = dist + (size_t)bb * N_ * N_;
#pragma unroll
    for (int mt = 0; mt < 4; ++mt) {
#pragma unroll
        for (int r = 0; r < 4; ++r) {
            int row = r0 + wm * 64 + mt * 16 + quad * 4 + r;
            float sqr = sq[base + row];
#pragma unroll
            for (int nt = 0; nt < 4; ++nt)
                dbase[(size_t)row * N_ + c0 + wn * 64 + nt * 16 + nl] =
                    2.f * acc[mt][nt][r] - sqr - sqc[nt];
        }
    }
}

// ---------------------------------------------------------------- Y|Z GEMM body
template <int CP, int NOUT>
__device__ __forceinline__ void gemmyz_body(unsigned short* smem,
                                            const unsigned short* __restrict__ Hh,
                                            const unsigned short* __restrict__ Hl,
                                            const unsigned short* __restrict__ Wh,
                                            const unsigned short* __restrict__ Wl,
                                            const float* __restrict__ bias2,
                                            float* __restrict__ YZ, int yb) {
    constexpr int KC = CP / 32;
    constexpr int NTt = NOUT / 16;
    constexpr int STR = 40;
    unsigned short* As = smem;
    int t = threadIdx.x;
    int m0 = (yb & 63) * 128;
    int n0 = (yb >> 6) * 128;
    int lane = t & 63, wave = t >> 6, quad = lane >> 4, nl = lane & 15;
    int wm = wave >> 1, wn = wave & 1;

    f32x4 acc[4][4];
#pragma unroll
    for (int mt = 0; mt < 4; ++mt)
#pragma unroll
        for (int nt = 0; nt < 4; ++nt) acc[mt][nt] = (f32x4){0.f, 0.f, 0.f, 0.f};

    for (int kc = 0; kc < KC; ++kc) {
        if (kc) __syncthreads();
#pragma unroll
        for (int i = 0; i < 2; ++i) {
            int cid = t + i * 256;
            int row = cid >> 2, j = cid & 3;
            size_t src = ((size_t)(m0 + row)) * CP + kc * 32 + 8 * j;
            int dst = row * STR + 8 * j;
            *(short8*)&As[dst] = *(const short8*)&Hh[src];
            *(short8*)&As[128 * STR + dst] = *(const short8*)&Hl[src];
        }
        __syncthreads();
        short8 ah[4], al[4];
#pragma unroll
        for (int mt = 0; mt < 4; ++mt) {
            int off = (wm * 64 + mt * 16 + nl) * STR + quad * 8;
            ah[mt] = *(const short8*)&As[off];
            al[mt] = *(const short8*)&As[128 * STR + off];
        }
#pragma unroll
        for (int nt = 0; nt < 4; ++nt) {
            int ntg = (n0 >> 4) + wn * 4 + nt;
            size_t bpos = ((size_t)(kc * NTt + ntg) * 64 + lane) * 8;
            short8 bh = *(const short8*)&Wh[bpos];
            short8 bl = *(const short8*)&Wl[bpos];
#pragma unroll
            for (int mt = 0; mt < 4; ++mt) {
                acc[mt][nt] = __builtin_amdgcn_mfma_f32_16x16x32_bf16(ah[mt], bh, acc[mt][nt], 0, 0, 0);
                acc[mt][nt] = __builtin_amdgcn_mfma_f32_16x16x32_bf16(ah[mt], bl, acc[mt][nt], 0, 0, 0);
                acc[mt][nt] = __builtin_amdgcn_mfma_f32_16x16x32_bf16(al[mt], bh, acc[mt][nt], 0, 0, 0);
            }
        }
    }
#pragma unroll
    for (int nt = 0; nt < 4; ++nt) {
        int col = n0 + wn * 64 + nt * 16 + nl;
        float bv = bias2[col];
#pragma unroll
        for (int mt = 0; mt < 4; ++mt) {
#pragma unroll
            for (int r = 0; r < 4; ++r) {
                int row = m0 + wm * 64 + mt * 16 + quad * 4 + r;
                YZ[(size_t)row * NOUT + col] = acc[mt][nt][r] + bv;
            }
        }
    }
}

// ---------------------------------------------------------------- merged dist+YZ
template <int CP, int NOUT>
__global__ __launch_bounds__(256) void distyz_kernel(const unsigned short* __restrict__ Hh,
                                                     const unsigned short* __restrict__ Hl,
                                                     const float* __restrict__ sq,
                                                     float* __restrict__ dist,
                                                     const unsigned short* __restrict__ Wh,
                                                     const unsigned short* __restrict__ Wl,
                                                     const float* __restrict__ bias2,
                                                     float* __restrict__ YZ) {
    __shared__ unsigned short smem[4 * 128 * 40];
    if (blockIdx.x < 512)
        distg_body<CP>(smem, Hh, Hl, sq, dist, blockIdx.x);
    else
        gemmyz_body<CP, NOUT>(smem, Hh, Hl, Wh, Wl, bias2, YZ, blockIdx.x - 512);
}

// ---------------------------------------------------------------- L1: dist + y1z1 merged
__global__ __launch_bounds__(256) void dist1y_kernel(const unsigned short* __restrict__ Hh,
                                                     const unsigned short* __restrict__ Hl,
                                                     const float* __restrict__ sq,
                                                     float* __restrict__ dist,
                                                     const float* __restrict__ x,
                                                     const float* __restrict__ wdT,
                                                     const float* __restrict__ wcdT,
                                                     const float* __restrict__ bias1,
                                                     float* __restrict__ YZ) {
    __shared__ unsigned short smem[4 * 128 * 40];
    if (blockIdx.x < 512) {
        distg_body<32>(smem, Hh, Hl, sq, dist, blockIdx.x);
    } else {
        int t = threadIdx.x;
        int p = (blockIdx.x - 512) * 4 + (t >> 6);
        int o = t & 63;
        float x0 = x[3 * p], x1 = x[3 * p + 1], x2 = x[3 * p + 2];
        float y = x0 * wdT[o] + x1 * wdT[64 + o] + x2 * wdT[128 + o];
        float z = bias1[o] + x0 * wcdT[o] + x1 * wcdT[64 + o] + x2 * wcdT[128 + o];
        YZ[(size_t)p * 128 + o] = y;
        YZ[(size_t)p * 128 + 64 + o] = z;
    }
}

// ---------------------------------------------------------------- top-20 select (per-wave body)
__device__ __forceinline__ unsigned int fkey(float f) {
    unsigned int u = __float_as_uint(f);
    return (u & 0x80000000u) ? ~u : (u | 0x80000000u);
}

__device__ __forceinline__ u64 tree16(const u64* v) {
    u64 t0[8];
#pragma unroll
    for (int s = 0; s < 8; ++s) t0[s] = v[2 * s] > v[2 * s + 1] ? v[2 * s] : v[2 * s + 1];
#pragma unroll
    for (int s = 0; s < 4; ++s) t0[s] = t0[2 * s] > t0[2 * s + 1] ? t0[2 * s] : t0[2 * s + 1];
    t0[0] = t0[0] > t0[1] ? t0[0] : t0[1];
    t0[2] = t0[2] > t0[3] ? t0[2] : t0[3];
    return t0[0] > t0[2] ? t0[0] : t0[2];
}

__device__ __forceinline__ u64 wave_sort_desc(u64 v, int lane) {
#pragma unroll
    for (int k2 = 2; k2 <= 64; k2 <<= 1) {
#pragma unroll
        for (int j = k2 >> 1; j > 0; j >>= 1) {
            u64 o = __shfl_xor(v, j);
            bool desc = ((lane & k2) == 0);
            bool lower = ((lane & j) == 0);
            u64 mx = v > o ? v : o;
            u64 mn = v > o ? o : v;
            v = (desc == lower) ? mx : mn;
        }
    }
    return v;
}

// one wave selects the top-20 set of a 1024-col dist row into LDS nidxrow[20]
__device__ __forceinline__ void sel_row(const float* __restrict__ d, int* nidxrow,
                                        u64* candbuf, int lane) {
    int c0 = lane * 16;
    u64 kk[16];
#pragma unroll
    for (int i = 0; i < 4; ++i) {
        float4 a = *(const float4*)&d[c0 + 4 * i];
        float av[4] = {a.x, a.y, a.z, a.w};
#pragma unroll
        for (int e = 0; e < 4; ++e) {
            int c = c0 + 4 * i + e;
            kk[4 * i + e] = ((u64)fkey(av[e]) << 32) | (unsigned int)(~c);
        }
    }
    u64 lm = tree16(kk);
    u64 lms = wave_sort_desc(lm, lane);
    u64 tau = __shfl(lms, 19);

    int cnt = 0;
#pragma unroll
    for (int i = 0; i < 16; ++i) cnt += (kk[i] >= tau) ? 1 : 0;
    int incl = cnt;
#pragma unroll
    for (int dd = 1; dd < 64; dd <<= 1) {
        int n = __shfl_up(incl, dd);
        if (lane >= dd) incl += n;
    }
    int excl = incl - cnt;
    int Ctot = __shfl(incl, 63);

    if (Ctot <= 64) {
        candbuf[lane] = 0ull;
        __builtin_amdgcn_wave_barrier();
        int pos = excl;
#pragma unroll
        for (int i = 0; i < 16; ++i) {
            if (kk[i] >= tau) { candbuf[pos] = kk[i]; ++pos; }
        }
        __builtin_amdgcn_wave_barrier();
        u64 c = candbuf[lane];
        c = wave_sort_desc(c, lane);
        if (lane < K_) nidxrow[lane] = (int)(~(unsigned int)c);
    } else {
        for (int it = 0; it < K_; ++it) {
            u64 m = tree16(kk);
#pragma unroll
            for (int off = 32; off; off >>= 1) {
                u64 o = __shfl_xor(m, off);
                m = o > m ? o : m;
            }
            if (lane == 0) nidxrow[it] = (int)(~(unsigned int)m);
#pragma unroll
            for (int j = 0; j < 16; ++j) kk[j] = (kk[j] == m) ? 0ull : kk[j];
        }
    }
}

// ---------------------------------------------------------------- fused select + gather + max + lrelu (+split)
template <int COUT, bool WRITE_H, bool WRITE_NEXT>
__global__ __launch_bounds__(256) void selgmx_kernel(const float* __restrict__ dist,
                                                     const float* __restrict__ YZ,
                                                     unsigned short* __restrict__ Hh,
                                                     unsigned short* __restrict__ Hl,
                                                     float* __restrict__ sq,
                                                     float* __restrict__ h) {
    constexpr int NOUT = 2 * COUT;
    constexpr int PPG = 256 / COUT;
    __shared__ int nidx[PPG][K_];
    __shared__ u64 cand[PPG][64];
    __shared__ float part[4];
    int t = threadIdx.x, wave = t >> 6, lane = t & 63;
    int p0 = blockIdx.x * PPG;

    if (wave < PPG)
        sel_row(dist + (size_t)(p0 + wave) * N_, nidx[wave], cand[wave], lane);
    __syncthreads();

    int pg = t / COUT, o = t % COUT, p = p0 + pg;
    size_t ybase = (size_t)(p >> 10) << 10;
    float m = -INFINITY;
#pragma unroll
    for (int k = 0; k < K_; ++k)
        m = fmaxf(m, YZ[(ybase + nidx[pg][k]) * NOUT + o]);
    float val = m + YZ[(size_t)p * NOUT + COUT + o];
    val = (val >= 0.f) ? val : 0.2f * val;
    if constexpr (WRITE_H) h[(size_t)p * COUT + o] = val;
    if constexpr (WRITE_NEXT) {
        unsigned short hi, lo;
        bf16split(val, hi, lo);
        Hh[(size_t)p * COUT + o] = hi;
        Hl[(size_t)p * COUT + o] = lo;
        float s = val * val;
#pragma unroll
        for (int d = 32; d; d >>= 1) s += __shfl_xor(s, d);
        if (lane == 0) part[wave] = s;
        __syncthreads();
        if (t < PPG) {
            constexpr int WPP = COUT / 64;
            float tot = 0.f;
#pragma unroll
            for (int w2 = 0; w2 < WPP; ++w2) tot += part[t * WPP + w2];
            sq[p0 + t] = tot;
        }
    }
}

// ---------------------------------------------------------------- setup: split(x) + all weight prep
__device__ __forceinline__ void prep_mfma2_elem(int e, int CIN, int COUT_,
                                                const float* w, const float* g,
                                                const float* bb, const float* m,
                                                const float* v,
                                                unsigned short* Wh, unsigned short* Wl,
                                                float* bias2) {
    int NOUT = 2 * COUT_;
    int NT = NOUT / 16;
    int n = e % NOUT, k = e / NOUT;
    int o = (n < COUT_) ? n : n - COUT_;
    float a = g[o] / sqrtf(v[o] + EPS_);
    float wv = (n < COUT_) ? a * w[o * 2 * CIN + k]
                           : a * (w[o * 2 * CIN + CIN + k] - w[o * 2 * CIN + k]);
    unsigned short hs, ls;
    bf16split(wv, hs, ls);
    int kc = k >> 5, ko = k & 31, quad = ko >> 3, j = ko & 7;
    int nt = n >> 4, nl = n & 15;
    size_t pos = ((size_t)(kc * NT + nt) * 64 + quad * 16 + nl) * 8 + j;
    Wh[pos] = hs;
    Wl[pos] = ls;
    if (k == 0) bias2[n] = (n < COUT_) ? 0.f : (bb[o] - m[o] * a);
}

__global__ __launch_bounds__(256) void setup_kernel(
    const float* __restrict__ x, unsigned short* __restrict__ Hh,
    unsigned short* __restrict__ Hl, float* __restrict__ sq,
    const float* __restrict__ w1, const float* __restrict__ g1, const float* __restrict__ bb1,
    const float* __restrict__ m1, const float* __restrict__ v1,
    const float* __restrict__ w2, const float* __restrict__ g2, const float* __restrict__ bb2,
    const float* __restrict__ m2, const float* __restrict__ v2,
    const float* __restrict__ w3, const float* __restrict__ g3, const float* __restrict__ bb3,
    const float* __restrict__ m3, const float* __restrict__ v3,
    const float* __restrict__ w4, const float* __restrict__ g4, const float* __restrict__ bb4,
    const float* __restrict__ m4, const float* __restrict__ v4,
    float* __restrict__ wd, float* __restrict__ wcd, float* __restrict__ bias1,
    unsigned short* __restrict__ Wh2, unsigned short* __restrict__ Wl2, float* __restrict__ b22,
    unsigned short* __restrict__ Wh3, unsigned short* __restrict__ Wl3, float* __restrict__ b23,
    unsigned short* __restrict__ Wh4, unsigned short* __restrict__ Wl4, float* __restrict__ b24) {
    int t = threadIdx.x;
    if (blockIdx.x < 32) {   // split: x (B*N,3) -> Hh/Hl padded CP=32 + sq
        int p = blockIdx.x * 256 + t;
        const float* r = x + (size_t)p * 3;
        unsigned short hb[32], lb[32];
        float s = 0.f;
#pragma unroll
        for (int c = 0; c < 3; ++c) {
            float v = r[c];
            s += v * v;
            bf16split(v, hb[c], lb[c]);
        }
#pragma unroll
        for (int c = 3; c < 32; ++c) { hb[c] = 0; lb[c] = 0; }
        sq[p] = s;
#pragma unroll
        for (int i = 0; i < 4; ++i) {
            *(short8*)&Hh[(size_t)p * 32 + 8 * i] = *(const short8*)&hb[8 * i];
            *(short8*)&Hl[(size_t)p * 32 + 8 * i] = *(const short8*)&lb[8 * i];
        }
        return;
    }
    int e = (blockIdx.x - 32) * 256 + t;
    if (e < 192) {
        int o = e % 64, i = e / 64;
        float a = g1[o] / sqrtf(v1[o] + EPS_);
        float wdv = w1[o * 6 + i];
        wd[e] = a * wdv;
        wcd[e] = a * (w1[o * 6 + 3 + i] - wdv);
        if (i == 0) bias1[o] = bb1[o] - m1[o] * a;
    } else if (e < 192 + 8192) {
        prep_mfma2_elem(e - 192, 64, 64, w2, g2, bb2, m2, v2, Wh2, Wl2, b22);
    } else if (e < 192 + 8192 + 16384) {
        prep_mfma2_elem(e - 8384, 64, 128, w3, g3, bb3, m3, v3, Wh3, Wl3, b23);
    } else if (e < 192 + 8192 + 16384 + 65536) {
        prep_mfma2_elem(e - 24768, 128, 256, w4, g4, bb4, m4, v4, Wh4, Wl4, b24);
    }
}

// ---------------------------------------------------------------- pools (both widths per launch)
__global__ __launch_bounds__(256) void pool1_all(const float* __restrict__ h3,
                                                 const float* __restrict__ h4,
                                                 float* __restrict__ p128,
                                                 float* __restrict__ p256) {
    __shared__ float red[4][64];
    int bid = blockIdx.x;
    const float* h;
    float* part;
    int C, bb, cb, z;
    if (bid < 256) {  // C=128
        z = bid & 15; cb = (bid >> 4) & 1; bb = bid >> 5;
        C = 128; h = h3; part = p128;
    } else {          // C=256
        int e = bid - 256;
        z = e & 15; cb = (e >> 4) & 3; bb = e >> 6;
        C = 256; h = h4; part = p256;
    }
    int lane = threadIdx.x & 63, sl = threadIdx.x >> 6;
    int c = cb * 64 + lane;
    const float* hb = h + (size_t)bb * N_ * C;
    int n0 = z * 64 + sl * 16;
    float mx = -INFINITY;
#pragma unroll
    for (int i = 0; i < 16; ++i) mx = fmaxf(mx, hb[(size_t)(n0 + i) * C + c]);
    red[sl][lane] = mx;
    __syncthreads();
    if (sl == 0) {
        mx = fmaxf(fmaxf(red[0][lane], red[1][lane]), fmaxf(red[2][lane], red[3][lane]));
        part[((size_t)bb * 16 + z) * C + c] = mx;
    }
}

__global__ __launch_bounds__(64) void pool2_all(const float* __restrict__ p128,
                                                const float* __restrict__ p256,
                                                float* __restrict__ f) {
    int bid = blockIdx.x;
    const float* part;
    int C, bb, cb, off;
    if (bid < 16) { cb = bid & 1; bb = bid >> 1; C = 128; part = p128; off = 0; }
    else { int e = bid - 16; cb = e & 3; bb = e >> 2; C = 256; part = p256; off = 128; }
    int c = cb * 64 + threadIdx.x;
    float mx = -INFINITY;
#pragma unroll
    for (int z = 0; z < 16; ++z)
        mx = fmaxf(mx, part[((size_t)bb * 16 + z) * C + c]);
    f[bb * 384 + off + c] = mx;
}

// ---------------------------------------------------------------- FC tail
__global__ __launch_bounds__(128) void fc_tail(
    const float* __restrict__ f, const float* __restrict__ f1w,
    const float* __restrict__ f1b, const float* __restrict__ n1g,
    const float* __restrict__ n1b, const float* __restrict__ n1m,
    const float* __restrict__ n1v, const float* __restrict__ f2w,
    const float* __restrict__ f2b, const float* __restrict__ n2g,
    const float* __restrict__ n2b, const float* __restrict__ n2m,
    const float* __restrict__ n2v, const float* __restrict__ f3w,
    const float* __restrict__ f3b, float* __restrict__ out) {
    __shared__ float fb[384];
    __shared__ float s1[128];
    __shared__ float s2[16];
    int bb = blockIdx.x, t = threadIdx.x;
    for (int j = t; j < 384; j += 128) fb[j] = f[bb * 384 + j];
    __syncthreads();
    float a = f1b[t];
    for (int j = 0; j < 384; ++j) a += f1w[t * 384 + j] * fb[j];
    a = (a - n1m[t]) * (n1g[t] / sqrtf(n1v[t] + EPS_)) + n1b[t];
    s1[t] = fmaxf(a, 0.f);
    __syncthreads();
    if (t < 16) {
        float a2 = f2b[t];
        for (int j = 0; j < 128; ++j) a2 += f2w[t * 128 + j] * s1[j];
        a2 = (a2 - n2m[t]) * (n2g[t] / sqrtf(n2v[t] + EPS_)) + n2b[t];
        s2[t] = fmaxf(a2, 0.f);
    }
    __syncthreads();
    if (t == 0) {
        float a3 = f3b[0];
        for (int j = 0; j < 16; ++j) a3 += f3w[j] * s2[j];
        out[bb] = a3;
    }
}

// ---------------------------------------------------------------- launch
extern "C" void kernel_launch(void* const* d_in, const int* in_sizes, int n_in,
                              void* d_out, int out_size, void* d_ws, size_t ws_size,
                              hipStream_t stream) {
    const float* x = (const float*)d_in[0];
    const float* cw[4] = {(const float*)d_in[1], (const float*)d_in[6],
                          (const float*)d_in[11], (const float*)d_in[16]};
    const float* cg[4] = {(const float*)d_in[2], (const float*)d_in[7],
                          (const float*)d_in[12], (const float*)d_in[17]};
    const float* cb[4] = {(const float*)d_in[3], (const float*)d_in[8],
                          (const float*)d_in[13], (const float*)d_in[18]};
    const float* cm[4] = {(const float*)d_in[4], (const float*)d_in[9],
                          (const float*)d_in[14], (const float*)d_in[19]};
    const float* cv[4] = {(const float*)d_in[5], (const float*)d_in[10],
                          (const float*)d_in[15], (const float*)d_in[20]};
    const float* f1w = (const float*)d_in[21];
    const float* f1b = (const float*)d_in[22];
    const float* n1g = (const float*)d_in[23];
    const float* n1b = (const float*)d_in[24];
    const float* n1m = (const float*)d_in[25];
    const float* n1v = (const float*)d_in[26];
    const float* f2w = (const float*)d_in[27];
    const float* f2b = (const float*)d_in[28];
    const float* n2g = (const float*)d_in[29];
    const float* n2b = (const float*)d_in[30];
    const float* n2m = (const float*)d_in[31];
    const float* n2v = (const float*)d_in[32];
    const float* f3w = (const float*)d_in[33];
    const float* f3b = (const float*)d_in[34];
    float* out = (float*)d_out;

    char* ws = (char*)d_ws;
    size_t off = 0;
    auto alloc = [&](size_t bytes) {
        void* p = ws + off;
        off += (bytes + 255) & ~(size_t)255;
        return p;
    };
    float* sq = (float*)alloc(B_ * N_ * 4);
    float* h3 = (float*)alloc((size_t)B_ * N_ * 128 * 4);
    float* h4 = (float*)alloc((size_t)B_ * N_ * 256 * 4);
    float* wd = (float*)alloc(3 * 64 * 4);
    float* wcd = (float*)alloc(3 * 64 * 4);
    float* bias1 = (float*)alloc(64 * 4);
    float* b22 = (float*)alloc(128 * 4);
    float* b23 = (float*)alloc(256 * 4);
    float* b24 = (float*)alloc(512 * 4);
    float* f = (float*)alloc(B_ * 384 * 4);
    float* p128 = (float*)alloc((size_t)B_ * 16 * 128 * 4);
    float* p256 = (float*)alloc((size_t)B_ * 16 * 256 * 4);
    unsigned short* Wh2 = (unsigned short*)alloc(64 * 128 * 2);
    unsigned short* Wl2 = (unsigned short*)alloc(64 * 128 * 2);
    unsigned short* Wh3 = (unsigned short*)alloc(64 * 256 * 2);
    unsigned short* Wl3 = (unsigned short*)alloc(64 * 256 * 2);
    unsigned short* Wh4 = (unsigned short*)alloc(128 * 512 * 2);
    unsigned short* Wl4 = (unsigned short*)alloc(128 * 512 * 2);
    unsigned short* Hh = (unsigned short*)alloc((size_t)B_ * N_ * 128 * 2);
    unsigned short* Hl = (unsigned short*)alloc((size_t)B_ * N_ * 128 * 2);
    float* dist = (float*)alloc((size_t)B_ * N_ * N_ * 4);
    float* YZ = (float*)alloc((size_t)B_ * N_ * 512 * 4);
    (void)ws_size; (void)in_sizes; (void)n_in; (void)out_size;

    // ---- setup: split(x) + all weight prep (one launch)
    setup_kernel<<<32 + (192 + 8192 + 16384 + 65536 + 255) / 256, 256, 0, stream>>>(
        x, Hh, Hl, sq,
        cw[0], cg[0], cb[0], cm[0], cv[0], cw[1], cg[1], cb[1], cm[1], cv[1],
        cw[2], cg[2], cb[2], cm[2], cv[2], cw[3], cg[3], cb[3], cm[3], cv[3],
        wd, wcd, bias1, Wh2, Wl2, b22, Wh3, Wl3, b23, Wh4, Wl4, b24);

    // ---- layer 1: 3 -> 64  (dist<32> + y1z1 in one launch)
    dist1y_kernel<<<512 + 2048, 256, 0, stream>>>(Hh, Hl, sq, dist, x, wd, wcd, bias1, YZ);
    selgmx_kernel<64, false, true><<<B_ * N_ / 4, 256, 0, stream>>>(dist, YZ, Hh, Hl, sq, nullptr);

    // ---- layer 2: 64 -> 64
    distyz_kernel<64, 128><<<512 + 64, 256, 0, stream>>>(Hh, Hl, sq, dist, Wh2, Wl2, b22, YZ);
    selgmx_kernel<64, false, true><<<B_ * N_ / 4, 256, 0, stream>>>(dist, YZ, Hh, Hl, sq, nullptr);

    // ---- layer 3: 64 -> 128
    distyz_kernel<64, 256><<<512 + 128, 256, 0, stream>>>(Hh, Hl, sq, dist, Wh3, Wl3, b23, YZ);
    selgmx_kernel<128, true, true><<<B_ * N_ / 2, 256, 0, stream>>>(dist, YZ, Hh, Hl, sq, h3);

    // ---- layer 4: 128 -> 256
    distyz_kernel<128, 512><<<512 + 256, 256, 0, stream>>>(Hh, Hl, sq, dist, Wh4, Wl4, b24, YZ);
    selgmx_kernel<256, true, false><<<B_ * N_, 256, 0, stream>>>(dist, YZ, nullptr, nullptr, nullptr, h4);

    // ---- pooling + FC tail
    pool1_all<<<256 + 512, 256, 0, stream>>>(h3, h4, p128, p256);
    pool2_all<<<16 + 32, 64, 0, stream>>>(p128, p256, f);
    fc_tail<<<B_, 128, 0, stream>>>(f, f1w, f1b, n1g, n1b, n1m, n1v, f2w, f2b, n2g, n2b,
                                    n2m, n2v, f3w, f3b, out);
}

// Round 13
// 272.624 us; speedup vs baseline: 5.6611x; 1.0448x over previous
//
#include <hip/hip_runtime.h>
#include <math.h>

constexpr int B_ = 8;
constexpr int N_ = 1024;
constexpr int K_ = 20;
constexpr float EPS_ = 1e-5f;

typedef __attribute__((ext_vector_type(8))) short short8;
typedef __attribute__((ext_vector_type(4))) float f32x4;
typedef unsigned long long u64;

// hi/lo bf16 split (RNE both halves)
__device__ __forceinline__ void bf16split(float x, unsigned short& h, unsigned short& l) {
    unsigned u = __float_as_uint(x);
    unsigned rh = (u + 0x7FFFu + ((u >> 16) & 1u)) >> 16;
    h = (unsigned short)rh;
    float lof = x - __uint_as_float(rh << 16);
    unsigned ul = __float_as_uint(lof);
    l = (unsigned short)((ul + 0x7FFFu + ((ul >> 16) & 1u)) >> 16);
}

// ---------------------------------------------------------------- distance GEMM body
// bid layout (XCD affinity): bb = bid & 7  ->  batch b runs on XCD b (%8 round-robin)
template <int CP>
__device__ __forceinline__ void distg_body(unsigned short* smem,
                                           const unsigned short* __restrict__ Hh,
                                           const unsigned short* __restrict__ Hl,
                                           const float* __restrict__ sq,
                                           float* __restrict__ dist, int bid) {
    constexpr int KC = CP / 32;
    constexpr int STR = 40;
    unsigned short* As = smem;
    unsigned short* Bs = smem + 2 * 128 * STR;
    int t = threadIdx.x;
    int bb = bid & 7;
    int r0 = ((bid >> 6) & 7) * 128;
    int c0 = ((bid >> 3) & 7) * 128;
    size_t base = (size_t)bb * N_;
    int lane = t & 63, wave = t >> 6, quad = lane >> 4, nl = lane & 15;
    int wm = wave >> 1, wn = wave & 1;

    f32x4 acc[4][4];
#pragma unroll
    for (int mt = 0; mt < 4; ++mt)
#pragma unroll
        for (int nt = 0; nt < 4; ++nt) acc[mt][nt] = (f32x4){0.f, 0.f, 0.f, 0.f};

    for (int kc = 0; kc < KC; ++kc) {
        if (kc) __syncthreads();
#pragma unroll
        for (int i = 0; i < 2; ++i) {
            int cid = t + i * 256;
            int row = cid >> 2, j = cid & 3;
            size_t asrc = (base + r0 + row) * CP + kc * 32 + 8 * j;
            size_t bsrc = (base + c0 + row) * CP + kc * 32 + 8 * j;
            int dst = row * STR + 8 * j;
            *(short8*)&As[dst] = *(const short8*)&Hh[asrc];
            *(short8*)&As[128 * STR + dst] = *(const short8*)&Hl[asrc];
            *(short8*)&Bs[dst] = *(const short8*)&Hh[bsrc];
            *(short8*)&Bs[128 * STR + dst] = *(const short8*)&Hl[bsrc];
        }
        __syncthreads();
        short8 ah[4], al[4];
#pragma unroll
        for (int mt = 0; mt < 4; ++mt) {
            int off = (wm * 64 + mt * 16 + nl) * STR + quad * 8;
            ah[mt] = *(const short8*)&As[off];
            al[mt] = *(const short8*)&As[128 * STR + off];
        }
#pragma unroll
        for (int nt = 0; nt < 4; ++nt) {
            int off = (wn * 64 + nt * 16 + nl) * STR + quad * 8;
            short8 bh = *(const short8*)&Bs[off];
            short8 bl = *(const short8*)&Bs[128 * STR + off];
#pragma unroll
            for (int mt = 0; mt < 4; ++mt) {
                acc[mt][nt] = __builtin_amdgcn_mfma_f32_16x16x32_bf16(ah[mt], bh, acc[mt][nt], 0, 0, 0);
                acc[mt][nt] = __builtin_amdgcn_mfma_f32_16x16x32_bf16(ah[mt], bl, acc[mt][nt], 0, 0, 0);
                acc[mt][nt] = __builtin_amdgcn_mfma_f32_16x16x32_bf16(al[mt], bh, acc[mt][nt], 0, 0, 0);
            }
        }
    }
    float sqc[4];
#pragma unroll
    for (int nt = 0; nt < 4; ++nt) sqc[nt] = sq[base + c0 + wn * 64 + nt * 16 + nl];
    float* dbase = dist + (size_t)bb * N_ * N_;
#pragma unroll
    for (int mt = 0; mt < 4; ++mt) {
#pragma unroll
        for (int r = 0; r < 4; ++r) {
            int row = r0 + wm * 64 + mt * 16 + quad * 4 + r;
            float sqr = sq[base + row];
#pragma unroll
            for (int nt = 0; nt < 4; ++nt)
                dbase[(size_t)row * N_ + c0 + wn * 64 + nt * 16 + nl] =
                    2.f * acc[mt][nt][r] - sqr - sqc[nt];
        }
    }
}

// ---------------------------------------------------------------- Y|Z GEMM body
// yb layout (XCD affinity): q = yb & 7 (batch), mband = (yb>>3)&7, ntile = yb>>6
template <int CP, int NOUT>
__device__ __forceinline__ void gemmyz_body(unsigned short* smem,
                                            const unsigned short* __restrict__ Hh,
                                            const unsigned short* __restrict__ Hl,
                                            const unsigned short* __restrict__ Wh,
                                            const unsigned short* __restrict__ Wl,
                                            const float* __restrict__ bias2,
                                            float* __restrict__ YZ, int yb) {
    constexpr int KC = CP / 32;
    constexpr int NTt = NOUT / 16;
    constexpr int STR = 40;
    unsigned short* As = smem;
    int t = threadIdx.x;
    int q = yb & 7, mband = (yb >> 3) & 7, ntile = yb >> 6;
    int m0 = (q * 8 + mband) * 128;
    int n0 = ntile * 128;
    int lane = t & 63, wave = t >> 6, quad = lane >> 4, nl = lane & 15;
    int wm = wave >> 1, wn = wave & 1;

    f32x4 acc[4][4];
#pragma unroll
    for (int mt = 0; mt < 4; ++mt)
#pragma unroll
        for (int nt = 0; nt < 4; ++nt) acc[mt][nt] = (f32x4){0.f, 0.f, 0.f, 0.f};

    for (int kc = 0; kc < KC; ++kc) {
        if (kc) __syncthreads();
#pragma unroll
        for (int i = 0; i < 2; ++i) {
            int cid = t + i * 256;
            int row = cid >> 2, j = cid & 3;
            size_t src = ((size_t)(m0 + row)) * CP + kc * 32 + 8 * j;
            int dst = row * STR + 8 * j;
            *(short8*)&As[dst] = *(const short8*)&Hh[src];
            *(short8*)&As[128 * STR + dst] = *(const short8*)&Hl[src];
        }
        __syncthreads();
        short8 ah[4], al[4];
#pragma unroll
        for (int mt = 0; mt < 4; ++mt) {
            int off = (wm * 64 + mt * 16 + nl) * STR + quad * 8;
            ah[mt] = *(const short8*)&As[off];
            al[mt] = *(const short8*)&As[128 * STR + off];
        }
#pragma unroll
        for (int nt = 0; nt < 4; ++nt) {
            int ntg = (n0 >> 4) + wn * 4 + nt;
            size_t bpos = ((size_t)(kc * NTt + ntg) * 64 + lane) * 8;
            short8 bh = *(const short8*)&Wh[bpos];
            short8 bl = *(const short8*)&Wl[bpos];
#pragma unroll
            for (int mt = 0; mt < 4; ++mt) {
                acc[mt][nt] = __builtin_amdgcn_mfma_f32_16x16x32_bf16(ah[mt], bh, acc[mt][nt], 0, 0, 0);
                acc[mt][nt] = __builtin_amdgcn_mfma_f32_16x16x32_bf16(ah[mt], bl, acc[mt][nt], 0, 0, 0);
                acc[mt][nt] = __builtin_amdgcn_mfma_f32_16x16x32_bf16(al[mt], bh, acc[mt][nt], 0, 0, 0);
            }
        }
    }
#pragma unroll
    for (int nt = 0; nt < 4; ++nt) {
        int col = n0 + wn * 64 + nt * 16 + nl;
        float bv = bias2[col];
#pragma unroll
        for (int mt = 0; mt < 4; ++mt) {
#pragma unroll
            for (int r = 0; r < 4; ++r) {
                int row = m0 + wm * 64 + mt * 16 + quad * 4 + r;
                YZ[(size_t)row * NOUT + col] = acc[mt][nt][r] + bv;
            }
        }
    }
}

// ---------------------------------------------------------------- merged dist+YZ
template <int CP, int NOUT>
__global__ __launch_bounds__(256) void distyz_kernel(const unsigned short* __restrict__ Hh,
                                                     const unsigned short* __restrict__ Hl,
                                                     const float* __restrict__ sq,
                                                     float* __restrict__ dist,
                                                     const unsigned short* __restrict__ Wh,
                                                     const unsigned short* __restrict__ Wl,
                                                     const float* __restrict__ bias2,
                                                     float* __restrict__ YZ) {
    __shared__ unsigned short smem[4 * 128 * 40];
    if (blockIdx.x < 512)
        distg_body<CP>(smem, Hh, Hl, sq, dist, blockIdx.x);
    else
        gemmyz_body<CP, NOUT>(smem, Hh, Hl, Wh, Wl, bias2, YZ, blockIdx.x - 512);
}

// ---------------------------------------------------------------- L1: dist + y1z1 merged
__global__ __launch_bounds__(256) void dist1y_kernel(const unsigned short* __restrict__ Hh,
                                                     const unsigned short* __restrict__ Hl,
                                                     const float* __restrict__ sq,
                                                     float* __restrict__ dist,
                                                     const float* __restrict__ x,
                                                     const float* __restrict__ wdT,
                                                     const float* __restrict__ wcdT,
                                                     const float* __restrict__ bias1,
                                                     float* __restrict__ YZ) {
    __shared__ unsigned short smem[4 * 128 * 40];
    if (blockIdx.x < 512) {
        distg_body<32>(smem, Hh, Hl, sq, dist, blockIdx.x);
    } else {
        int bid2 = blockIdx.x - 512;
        int t = threadIdx.x;
        int p = ((bid2 & 7) << 10) + ((bid2 >> 3) * 4) + (t >> 6);
        int o = t & 63;
        float x0 = x[3 * p], x1 = x[3 * p + 1], x2 = x[3 * p + 2];
        float y = x0 * wdT[o] + x1 * wdT[64 + o] + x2 * wdT[128 + o];
        float z = bias1[o] + x0 * wcdT[o] + x1 * wcdT[64 + o] + x2 * wcdT[128 + o];
        YZ[(size_t)p * 128 + o] = y;
        YZ[(size_t)p * 128 + 64 + o] = z;
    }
}

// ---------------------------------------------------------------- top-20 select (per-wave body)
__device__ __forceinline__ unsigned int fkey(float f) {
    unsigned int u = __float_as_uint(f);
    return (u & 0x80000000u) ? ~u : (u | 0x80000000u);
}

__device__ __forceinline__ u64 tree16(const u64* v) {
    u64 t0[8];
#pragma unroll
    for (int s = 0; s < 8; ++s) t0[s] = v[2 * s] > v[2 * s + 1] ? v[2 * s] : v[2 * s + 1];
#pragma unroll
    for (int s = 0; s < 4; ++s) t0[s] = t0[2 * s] > t0[2 * s + 1] ? t0[2 * s] : t0[2 * s + 1];
    t0[0] = t0[0] > t0[1] ? t0[0] : t0[1];
    t0[2] = t0[2] > t0[3] ? t0[2] : t0[3];
    return t0[0] > t0[2] ? t0[0] : t0[2];
}

__device__ __forceinline__ u64 wave_sort_desc(u64 v, int lane) {
#pragma unroll
    for (int k2 = 2; k2 <= 64; k2 <<= 1) {
#pragma unroll
        for (int j = k2 >> 1; j > 0; j >>= 1) {
            u64 o = __shfl_xor(v, j);
            bool desc = ((lane & k2) == 0);
            bool lower = ((lane & j) == 0);
            u64 mx = v > o ? v : o;
            u64 mn = v > o ? o : v;
            v = (desc == lower) ? mx : mn;
        }
    }
    return v;
}

// one wave selects the top-20 set of a 1024-col dist row into LDS nidxrow[20]
__device__ __forceinline__ void sel_row(const float* __restrict__ d, int* nidxrow,
                                        u64* candbuf, int lane) {
    int c0 = lane * 16;
    u64 kk[16];
#pragma unroll
    for (int i = 0; i < 4; ++i) {
        float4 a = *(const float4*)&d[c0 + 4 * i];
        float av[4] = {a.x, a.y, a.z, a.w};
#pragma unroll
        for (int e = 0; e < 4; ++e) {
            int c = c0 + 4 * i + e;
            kk[4 * i + e] = ((u64)fkey(av[e]) << 32) | (unsigned int)(~c);
        }
    }
    u64 lm = tree16(kk);
    u64 lms = wave_sort_desc(lm, lane);
    u64 tau = __shfl(lms, 19);

    int cnt = 0;
#pragma unroll
    for (int i = 0; i < 16; ++i) cnt += (kk[i] >= tau) ? 1 : 0;
    int incl = cnt;
#pragma unroll
    for (int dd = 1; dd < 64; dd <<= 1) {
        int n = __shfl_up(incl, dd);
        if (lane >= dd) incl += n;
    }
    int excl = incl - cnt;
    int Ctot = __shfl(incl, 63);

    if (Ctot <= 64) {
        candbuf[lane] = 0ull;
        __builtin_amdgcn_wave_barrier();
        int pos = excl;
#pragma unroll
        for (int i = 0; i < 16; ++i) {
            if (kk[i] >= tau) { candbuf[pos] = kk[i]; ++pos; }
        }
        __builtin_amdgcn_wave_barrier();
        u64 c = candbuf[lane];
        c = wave_sort_desc(c, lane);
        if (lane < K_) nidxrow[lane] = (int)(~(unsigned int)c);
    } else {
        for (int it = 0; it < K_; ++it) {
            u64 m = tree16(kk);
#pragma unroll
            for (int off = 32; off; off >>= 1) {
                u64 o = __shfl_xor(m, off);
                m = o > m ? o : m;
            }
            if (lane == 0) nidxrow[it] = (int)(~(unsigned int)m);
#pragma unroll
            for (int j = 0; j < 16; ++j) kk[j] = (kk[j] == m) ? 0ull : kk[j];
        }
    }
}

// ---------------------------------------------------------------- fused select + gather + max + lrelu (+split)
// blockIdx layout (XCD affinity): batch = blockIdx & 7
template <int COUT, bool WRITE_H, bool WRITE_NEXT>
__global__ __launch_bounds__(256) void selgmx_kernel(const float* __restrict__ dist,
                                                     const float* __restrict__ YZ,
                                                     unsigned short* __restrict__ Hh,
                                                     unsigned short* __restrict__ Hl,
                                                     float* __restrict__ sq,
                                                     float* __restrict__ h) {
    constexpr int NOUT = 2 * COUT;
    constexpr int PPG = 256 / COUT;
    __shared__ int nidx[PPG][K_];
    __shared__ u64 cand[PPG][64];
    __shared__ float part[4];
    int t = threadIdx.x, wave = t >> 6, lane = t & 63;
    int p0 = ((blockIdx.x & 7) << 10) + (blockIdx.x >> 3) * PPG;

    if (wave < PPG)
        sel_row(dist + (size_t)(p0 + wave) * N_, nidx[wave], cand[wave], lane);
    __syncthreads();

    int pg = t / COUT, o = t % COUT, p = p0 + pg;
    size_t ybase = (size_t)(p >> 10) << 10;
    float m = -INFINITY;
#pragma unroll
    for (int k = 0; k < K_; ++k)
        m = fmaxf(m, YZ[(ybase + nidx[pg][k]) * NOUT + o]);
    float val = m + YZ[(size_t)p * NOUT + COUT + o];
    val = (val >= 0.f) ? val : 0.2f * val;
    if constexpr (WRITE_H) h[(size_t)p * COUT + o] = val;
    if constexpr (WRITE_NEXT) {
        unsigned short hi, lo;
        bf16split(val, hi, lo);
        Hh[(size_t)p * COUT + o] = hi;
        Hl[(size_t)p * COUT + o] = lo;
        float s = val * val;
#pragma unroll
        for (int d = 32; d; d >>= 1) s += __shfl_xor(s, d);
        if (lane == 0) part[wave] = s;
        __syncthreads();
        if (t < PPG) {
            constexpr int WPP = COUT / 64;
            float tot = 0.f;
#pragma unroll
            for (int w2 = 0; w2 < WPP; ++w2) tot += part[t * WPP + w2];
            sq[p0 + t] = tot;
        }
    }
}

// ---------------------------------------------------------------- setup: split(x) + all weight prep
__device__ __forceinline__ void prep_mfma2_elem(int e, int CIN, int COUT_,
                                                const float* w, const float* g,
                                                const float* bb, const float* m,
                                                const float* v,
                                                unsigned short* Wh, unsigned short* Wl,
                                                float* bias2) {
    int NOUT = 2 * COUT_;
    int NT = NOUT / 16;
    int n = e % NOUT, k = e / NOUT;
    int o = (n < COUT_) ? n : n - COUT_;
    float a = g[o] / sqrtf(v[o] + EPS_);
    float wv = (n < COUT_) ? a * w[o * 2 * CIN + k]
                           : a * (w[o * 2 * CIN + CIN + k] - w[o * 2 * CIN + k]);
    unsigned short hs, ls;
    bf16split(wv, hs, ls);
    int kc = k >> 5, ko = k & 31, quad = ko >> 3, j = ko & 7;
    int nt = n >> 4, nl = n & 15;
    size_t pos = ((size_t)(kc * NT + nt) * 64 + quad * 16 + nl) * 8 + j;
    Wh[pos] = hs;
    Wl[pos] = ls;
    if (k == 0) bias2[n] = (n < COUT_) ? 0.f : (bb[o] - m[o] * a);
}

__global__ __launch_bounds__(256) void setup_kernel(
    const float* __restrict__ x, unsigned short* __restrict__ Hh,
    unsigned short* __restrict__ Hl, float* __restrict__ sq,
    const float* __restrict__ w1, const float* __restrict__ g1, const float* __restrict__ bb1,
    const float* __restrict__ m1, const float* __restrict__ v1,
    const float* __restrict__ w2, const float* __restrict__ g2, const float* __restrict__ bb2,
    const float* __restrict__ m2, const float* __restrict__ v2,
    const float* __restrict__ w3, const float* __restrict__ g3, const float* __restrict__ bb3,
    const float* __restrict__ m3, const float* __restrict__ v3,
    const float* __restrict__ w4, const float* __restrict__ g4, const float* __restrict__ bb4,
    const float* __restrict__ m4, const float* __restrict__ v4,
    float* __restrict__ wd, float* __restrict__ wcd, float* __restrict__ bias1,
    unsigned short* __restrict__ Wh2, unsigned short* __restrict__ Wl2, float* __restrict__ b22,
    unsigned short* __restrict__ Wh3, unsigned short* __restrict__ Wl3, float* __restrict__ b23,
    unsigned short* __restrict__ Wh4, unsigned short* __restrict__ Wl4, float* __restrict__ b24) {
    int t = threadIdx.x;
    if (blockIdx.x < 32) {
        int p = blockIdx.x * 256 + t;
        const float* r = x + (size_t)p * 3;
        unsigned short hb[32], lb[32];
        float s = 0.f;
#pragma unroll
        for (int c = 0; c < 3; ++c) {
            float v = r[c];
            s += v * v;
            bf16split(v, hb[c], lb[c]);
        }
#pragma unroll
        for (int c = 3; c < 32; ++c) { hb[c] = 0; lb[c] = 0; }
        sq[p] = s;
#pragma unroll
        for (int i = 0; i < 4; ++i) {
            *(short8*)&Hh[(size_t)p * 32 + 8 * i] = *(const short8*)&hb[8 * i];
            *(short8*)&Hl[(size_t)p * 32 + 8 * i] = *(const short8*)&lb[8 * i];
        }
        return;
    }
    int e = (blockIdx.x - 32) * 256 + t;
    if (e < 192) {
        int o = e % 64, i = e / 64;
        float a = g1[o] / sqrtf(v1[o] + EPS_);
        float wdv = w1[o * 6 + i];
        wd[e] = a * wdv;
        wcd[e] = a * (w1[o * 6 + 3 + i] - wdv);
        if (i == 0) bias1[o] = bb1[o] - m1[o] * a;
    } else if (e < 192 + 8192) {
        prep_mfma2_elem(e - 192, 64, 64, w2, g2, bb2, m2, v2, Wh2, Wl2, b22);
    } else if (e < 192 + 8192 + 16384) {
        prep_mfma2_elem(e - 8384, 64, 128, w3, g3, bb3, m3, v3, Wh3, Wl3, b23);
    } else if (e < 192 + 8192 + 16384 + 65536) {
        prep_mfma2_elem(e - 24768, 128, 256, w4, g4, bb4, m4, v4, Wh4, Wl4, b24);
    }
}

// ---------------------------------------------------------------- pool stage 1 (both widths)
__global__ __launch_bounds__(256) void pool1_all(const float* __restrict__ h3,
                                                 const float* __restrict__ h4,
                                                 float* __restrict__ p128,
                                                 float* __restrict__ p256) {
    __shared__ float red[4][64];
    int bid = blockIdx.x;
    const float* h;
    float* part;
    int C, bb, cb, z;
    if (bid < 256) {
        z = bid & 15; cb = (bid >> 4) & 1; bb = bid >> 5;
        C = 128; h = h3; part = p128;
    } else {
        int e = bid - 256;
        z = e & 15; cb = (e >> 4) & 3; bb = e >> 6;
        C = 256; h = h4; part = p256;
    }
    int lane = threadIdx.x & 63, sl = threadIdx.x >> 6;
    int c = cb * 64 + lane;
    const float* hb = h + (size_t)bb * N_ * C;
    int n0 = z * 64 + sl * 16;
    float mx = -INFINITY;
#pragma unroll
    for (int i = 0; i < 16; ++i) mx = fmaxf(mx, hb[(size_t)(n0 + i) * C + c]);
    red[sl][lane] = mx;
    __syncthreads();
    if (sl == 0) {
        mx = fmaxf(fmaxf(red[0][lane], red[1][lane]), fmaxf(red[2][lane], red[3][lane]));
        part[((size_t)bb * 16 + z) * C + c] = mx;
    }
}

// ---------------------------------------------------------------- FC tail (absorbs pool stage 2)
__global__ __launch_bounds__(128) void fc_tail(
    const float* __restrict__ p128, const float* __restrict__ p256,
    const float* __restrict__ f1w,
    const float* __restrict__ f1b, const float* __restrict__ n1g,
    const float* __restrict__ n1b, const float* __restrict__ n1m,
    const float* __restrict__ n1v, const float* __restrict__ f2w,
    const float* __restrict__ f2b, const float* __restrict__ n2g,
    const float* __restrict__ n2b, const float* __restrict__ n2m,
    const float* __restrict__ n2v, const float* __restrict__ f3w,
    const float* __restrict__ f3b, float* __restrict__ out) {
    __shared__ float fb[384];
    __shared__ float s1[128];
    __shared__ float s2[16];
    int bb = blockIdx.x, t = threadIdx.x;
    for (int j = t; j < 384; j += 128) {
        float mx = -INFINITY;
        if (j < 128) {
#pragma unroll
            for (int z = 0; z < 16; ++z)
                mx = fmaxf(mx, p128[((size_t)bb * 16 + z) * 128 + j]);
        } else {
            int c = j - 128;
#pragma unroll
            for (int z = 0; z < 16; ++z)
                mx = fmaxf(mx, p256[((size_t)bb * 16 + z) * 256 + c]);
        }
        fb[j] = mx;
    }
    __syncthreads();
    float a = f1b[t];
    for (int j = 0; j < 384; ++j) a += f1w[t * 384 + j] * fb[j];
    a = (a - n1m[t]) * (n1g[t] / sqrtf(n1v[t] + EPS_)) + n1b[t];
    s1[t] = fmaxf(a, 0.f);
    __syncthreads();
    if (t < 16) {
        float a2 = f2b[t];
        for (int j = 0; j < 128; ++j) a2 += f2w[t * 128 + j] * s1[j];
        a2 = (a2 - n2m[t]) * (n2g[t] / sqrtf(n2v[t] + EPS_)) + n2b[t];
        s2[t] = fmaxf(a2, 0.f);
    }
    __syncthreads();
    if (t == 0) {
        float a3 = f3b[0];
        for (int j = 0; j < 16; ++j) a3 += f3w[j] * s2[j];
        out[bb] = a3;
    }
}

// ---------------------------------------------------------------- launch
extern "C" void kernel_launch(void* const* d_in, const int* in_sizes, int n_in,
                              void* d_out, int out_size, void* d_ws, size_t ws_size,
                              hipStream_t stream) {
    const float* x = (const float*)d_in[0];
    const float* cw[4] = {(const float*)d_in[1], (const float*)d_in[6],
                          (const float*)d_in[11], (const float*)d_in[16]};
    const float* cg[4] = {(const float*)d_in[2], (const float*)d_in[7],
                          (const float*)d_in[12], (const float*)d_in[17]};
    const float* cb[4] = {(const float*)d_in[3], (const float*)d_in[8],
                          (const float*)d_in[13], (const float*)d_in[18]};
    const float* cm[4] = {(const float*)d_in[4], (const float*)d_in[9],
                          (const float*)d_in[14], (const float*)d_in[19]};
    const float* cv[4] = {(const float*)d_in[5], (const float*)d_in[10],
                          (const float*)d_in[15], (const float*)d_in[20]};
    const float* f1w = (const float*)d_in[21];
    const float* f1b = (const float*)d_in[22];
    const float* n1g = (const float*)d_in[23];
    const float* n1b = (const float*)d_in[24];
    const float* n1m = (const float*)d_in[25];
    const float* n1v = (const float*)d_in[26];
    const float* f2w = (const float*)d_in[27];
    const float* f2b = (const float*)d_in[28];
    const float* n2g = (const float*)d_in[29];
    const float* n2b = (const float*)d_in[30];
    const float* n2m = (const float*)d_in[31];
    const float* n2v = (const float*)d_in[32];
    const float* f3w = (const float*)d_in[33];
    const float* f3b = (const float*)d_in[34];
    float* out = (float*)d_out;

    char* ws = (char*)d_ws;
    size_t off = 0;
    auto alloc = [&](size_t bytes) {
        void* p = ws + off;
        off += (bytes + 255) & ~(size_t)255;
        return p;
    };
    float* sq = (float*)alloc(B_ * N_ * 4);
    float* h3 = (float*)alloc((size_t)B_ * N_ * 128 * 4);
    float* h4 = (float*)alloc((size_t)B_ * N_ * 256 * 4);
    float* wd = (float*)alloc(3 * 64 * 4);
    float* wcd = (float*)alloc(3 * 64 * 4);
    float* bias1 = (float*)alloc(64 * 4);
    float* b22 = (float*)alloc(128 * 4);
    float* b23 = (float*)alloc(256 * 4);
    float* b24 = (float*)alloc(512 * 4);
    float* p128 = (float*)alloc((size_t)B_ * 16 * 128 * 4);
    float* p256 = (float*)alloc((size_t)B_ * 16 * 256 * 4);
    unsigned short* Wh2 = (unsigned short*)alloc(64 * 128 * 2);
    unsigned short* Wl2 = (unsigned short*)alloc(64 * 128 * 2);
    unsigned short* Wh3 = (unsigned short*)alloc(64 * 256 * 2);
    unsigned short* Wl3 = (unsigned short*)alloc(64 * 256 * 2);
    unsigned short* Wh4 = (unsigned short*)alloc(128 * 512 * 2);
    unsigned short* Wl4 = (unsigned short*)alloc(128 * 512 * 2);
    unsigned short* Hh = (unsigned short*)alloc((size_t)B_ * N_ * 128 * 2);
    unsigned short* Hl = (unsigned short*)alloc((size_t)B_ * N_ * 128 * 2);
    float* dist = (float*)alloc((size_t)B_ * N_ * N_ * 4);
    float* YZ = (float*)alloc((size_t)B_ * N_ * 512 * 4);
    (void)ws_size; (void)in_sizes; (void)n_in; (void)out_size;

    // ---- setup: split(x) + all weight prep (one launch)
    setup_kernel<<<32 + (192 + 8192 + 16384 + 65536 + 255) / 256, 256, 0, stream>>>(
        x, Hh, Hl, sq,
        cw[0], cg[0], cb[0], cm[0], cv[0], cw[1], cg[1], cb[1], cm[1], cv[1],
        cw[2], cg[2], cb[2], cm[2], cv[2], cw[3], cg[3], cb[3], cm[3], cv[3],
        wd, wcd, bias1, Wh2, Wl2, b22, Wh3, Wl3, b23, Wh4, Wl4, b24);

    // ---- layer 1: 3 -> 64
    dist1y_kernel<<<512 + 2048, 256, 0, stream>>>(Hh, Hl, sq, dist, x, wd, wcd, bias1, YZ);
    selgmx_kernel<64, false, true><<<B_ * N_ / 4, 256, 0, stream>>>(dist, YZ, Hh, Hl, sq, nullptr);

    // ---- layer 2: 64 -> 64
    distyz_kernel<64, 128><<<512 + 64, 256, 0, stream>>>(Hh, Hl, sq, dist, Wh2, Wl2, b22, YZ);
    selgmx_kernel<64, false, true><<<B_ * N_ / 4, 256, 0, stream>>>(dist, YZ, Hh, Hl, sq, nullptr);

    // ---- layer 3: 64 -> 128
    distyz_kernel<64, 256><<<512 + 128, 256, 0, stream>>>(Hh, Hl, sq, dist, Wh3, Wl3, b23, YZ);
    selgmx_kernel<128, true, true><<<B_ * N_ / 2, 256, 0, stream>>>(dist, YZ, Hh, Hl, sq, h3);

    // ---- layer 4: 128 -> 256
    distyz_kernel<128, 512><<<512 + 256, 256, 0, stream>>>(Hh, Hl, sq, dist, Wh4, Wl4, b24, YZ);
    selgmx_kernel<256, true, false><<<B_ * N_, 256, 0, stream>>>(dist, YZ, nullptr, nullptr, nullptr, h4);

    // ---- pooling + FC tail (pool2 folded into fc_tail)
    pool1_all<<<256 + 512, 256, 0, stream>>>(h3, h4, p128, p256);
    fc_tail<<<B_, 128, 0, stream>>>(p128, p256, f1w, f1b, n1g, n1b, n1m, n1v, f2w, f2b,
                                    n2g, n2b, n2m, n2v, f3w, f3b, out);
}